// Round 1
// baseline (39822.855 us; speedup 1.0000x reference)
//
#include <hip/hip_runtime.h>
#include <stdint.h>

#define TSN 400
#define NB 16
#define HENC 512
#define HD2 1024
#define G3E 1536
#define G3D 3072
#define EMBD 300
#define AEMB 32
#define IN0 332
#define NV 50000
#define NEXT 50100
#define NTT 32
#define NEG_INF (-1.0e12f)

// ---------------- device-scope grid barrier (64 co-resident blocks) ----------------
__device__ __forceinline__ void gridbar(int* bar, int nblocks, int epoch) {
  __syncthreads();
  if (threadIdx.x == 0) {
    __threadfence();
    __hip_atomic_fetch_add(bar, 1, __ATOMIC_ACQ_REL, __HIP_MEMORY_SCOPE_AGENT);
    const int target = nblocks * epoch;
    while (__hip_atomic_load(bar, __ATOMIC_ACQUIRE, __HIP_MEMORY_SCOPE_AGENT) < target)
      __builtin_amdgcn_s_sleep(2);
    __threadfence();
  }
  __syncthreads();
}

// ---------------- gather/concat embeddings: X0[t][b][0:332] ----------------
__global__ __launch_bounds__(256) void k_embed(
    const float* __restrict__ enc_emb, const float* __restrict__ ans_emb,
    const int* __restrict__ input_s, const int* __restrict__ input_a,
    float* __restrict__ X0)
{
  long i = (long)blockIdx.x*256 + threadIdx.x;
  if (i >= (long)TSN*NB*IN0) return;
  int c = (int)(i % IN0);
  long r = i / IN0;
  int b = (int)(r % NB);
  int t = (int)(r / NB);
  float v;
  if (c < EMBD) v = enc_emb[(long)input_s[b*TSN + t]*EMBD + c];
  else          v = ans_emb[(long)input_a[b*TSN + t]*AEMB + (c - EMBD)];
  X0[i] = v;
}

// ---------------- decoder emb gather: EQ[s][b][0:300] ----------------
__global__ __launch_bounds__(256) void k_embq(
    const float* __restrict__ dec_emb, const int* __restrict__ input_q,
    float* __restrict__ EQ)
{
  long i = (long)blockIdx.x*256 + threadIdx.x;
  if (i >= (long)NTT*NB*EMBD) return;
  int c = (int)(i % EMBD);
  long r = i / EMBD;
  int b = (int)(r % NB);
  int s = (int)(r / NB);
  EQ[i] = dec_emb[(long)input_q[b*33 + s]*EMBD + c];
}

// ---------------- transpose: out[c][r] = in[r][c], out ld = R ----------------
__global__ __launch_bounds__(256) void k_transpose(
    const float* __restrict__ in, float* __restrict__ out, int R, int C, int ldin)
{
  __shared__ float tbuf[32][33];
  int r0 = blockIdx.x*32, c0 = blockIdx.y*32;
  int tx = threadIdx.x & 31, ty = threadIdx.x >> 5;
  #pragma unroll
  for (int i = 0; i < 32; i += 8) {
    int r = r0 + ty + i, c = c0 + tx;
    tbuf[ty+i][tx] = (r < R && c < C) ? in[(long)r*ldin + c] : 0.f;
  }
  __syncthreads();
  #pragma unroll
  for (int i = 0; i < 32; i += 8) {
    int c = c0 + ty + i, r = r0 + tx;
    if (c < C && r < R) out[(long)c*R + r] = tbuf[tx][ty+i];
  }
}

// ---------------- generic fp32 GEMM: C = act((accum?C:0) + A[M,K]*W[N,K]^T + bias) ----------------
__global__ __launch_bounds__(256) void k_gemm_nt(
    const float* __restrict__ Ab, const float* __restrict__ Wb,
    const float* __restrict__ bias, float* __restrict__ Cb,
    int M, int N, int K, int lda, int ldw, int ldc,
    long sA, long sW, long sC, int accum, int act)
{
  __shared__ float As[16][68];
  __shared__ float Ws[16][68];
  const float* A = Ab + (long)blockIdx.z * sA;
  const float* W = Wb + (long)blockIdx.z * sW;
  float* C = Cb + (long)blockIdx.z * sC;
  const int m0 = blockIdx.x*64, n0 = blockIdx.y*64;
  const int tid = threadIdx.x, tx = tid & 15, ty = tid >> 4;
  float acc[4][4] = {};
  for (int k0 = 0; k0 < K; k0 += 16) {
    #pragma unroll
    for (int i = 0; i < 4; ++i) {
      int li = tid + i*256;
      int r = li >> 4, c = li & 15;
      As[c][r] = (m0 + r < M && k0 + c < K) ? A[(long)(m0+r)*lda + k0 + c] : 0.f;
      Ws[c][r] = (n0 + r < N && k0 + c < K) ? W[(long)(n0+r)*ldw + k0 + c] : 0.f;
    }
    __syncthreads();
    #pragma unroll
    for (int k = 0; k < 16; ++k) {
      float4 av = *(const float4*)&As[k][ty*4];
      float4 bv = *(const float4*)&Ws[k][tx*4];
      acc[0][0] += av.x*bv.x; acc[0][1] += av.x*bv.y; acc[0][2] += av.x*bv.z; acc[0][3] += av.x*bv.w;
      acc[1][0] += av.y*bv.x; acc[1][1] += av.y*bv.y; acc[1][2] += av.y*bv.z; acc[1][3] += av.y*bv.w;
      acc[2][0] += av.z*bv.x; acc[2][1] += av.z*bv.y; acc[2][2] += av.z*bv.z; acc[2][3] += av.z*bv.w;
      acc[3][0] += av.w*bv.x; acc[3][1] += av.w*bv.y; acc[3][2] += av.w*bv.z; acc[3][3] += av.w*bv.w;
    }
    __syncthreads();
  }
  #pragma unroll
  for (int i = 0; i < 4; ++i) {
    int m = m0 + ty*4 + i;
    if (m >= M) continue;
    #pragma unroll
    for (int j = 0; j < 4; ++j) {
      int n = n0 + tx*4 + j;
      if (n >= N) continue;
      float v = acc[i][j];
      if (accum) v += C[(long)m*ldc + n];
      if (bias)  v += bias[n];
      if (act == 1) v = tanhf(v);
      else if (act == 2) v = 1.f/(1.f + expf(-v));
      C[(long)m*ldc + n] = v;
    }
  }
}

// ---------------- generic fp32 GEMM: C = A[M,K]*B[K,N] ----------------
__global__ __launch_bounds__(256) void k_gemm_nn(
    const float* __restrict__ Ab, const float* __restrict__ Bb,
    float* __restrict__ Cb, int M, int N, int K,
    int lda, int ldb, int ldc, long sA, long sB, long sC)
{
  __shared__ float As[16][68];
  __shared__ float Bs[16][68];
  const float* A = Ab + (long)blockIdx.z * sA;
  const float* Bm = Bb + (long)blockIdx.z * sB;
  float* C = Cb + (long)blockIdx.z * sC;
  const int m0 = blockIdx.x*64, n0 = blockIdx.y*64;
  const int tid = threadIdx.x, tx = tid & 15, ty = tid >> 4;
  float acc[4][4] = {};
  for (int k0 = 0; k0 < K; k0 += 16) {
    #pragma unroll
    for (int i = 0; i < 4; ++i) {
      int li = tid + i*256;
      int r = li >> 4, c = li & 15;
      As[c][r] = (m0 + r < M && k0 + c < K) ? A[(long)(m0+r)*lda + k0 + c] : 0.f;
      int kk = li >> 6, nn = li & 63;
      Bs[kk][nn] = (k0 + kk < K && n0 + nn < N) ? Bm[(long)(k0+kk)*ldb + n0 + nn] : 0.f;
    }
    __syncthreads();
    #pragma unroll
    for (int k = 0; k < 16; ++k) {
      float4 av = *(const float4*)&As[k][ty*4];
      float4 bv = *(const float4*)&Bs[k][tx*4];
      acc[0][0] += av.x*bv.x; acc[0][1] += av.x*bv.y; acc[0][2] += av.x*bv.z; acc[0][3] += av.x*bv.w;
      acc[1][0] += av.y*bv.x; acc[1][1] += av.y*bv.y; acc[1][2] += av.y*bv.z; acc[1][3] += av.y*bv.w;
      acc[2][0] += av.z*bv.x; acc[2][1] += av.z*bv.y; acc[2][2] += av.z*bv.z; acc[2][3] += av.z*bv.w;
      acc[3][0] += av.w*bv.x; acc[3][1] += av.w*bv.y; acc[3][2] += av.w*bv.z; acc[3][3] += av.w*bv.w;
    }
    __syncthreads();
  }
  #pragma unroll
  for (int i = 0; i < 4; ++i) {
    int m = m0 + ty*4 + i;
    if (m >= M) continue;
    #pragma unroll
    for (int j = 0; j < 4; ++j) {
      int n = n0 + tx*4 + j;
      if (n >= N) continue;
      C[(long)m*ldc + n] = acc[i][j];
    }
  }
}

// ---------------- persistent bidirectional GRU scan (one layer) ----------------
// 64 blocks x 256. Per step: phase1 computes K-split partials of h@Wh^T for both
// directions (4 b's, 1 j, chunk of 128 k per thread), phase2 combines gates.
__global__ __launch_bounds__(256) void k_scan(
    const float* __restrict__ GXf, const float* __restrict__ GXb,
    const float* __restrict__ WhT,  // [2][512][1536]
    const float* __restrict__ bh,   // [2][1536]
    float* __restrict__ Y,          // [400][16][1024]
    float* __restrict__ hfin,       // [16][1024]
    float* __restrict__ hbuf,       // [2 dir][2 ping][16][512]
    float* __restrict__ ghp,        // [4 ks][2 dir][16][1536]
    int* __restrict__ bar)
{
  const int bx = blockIdx.x, tid = threadIdx.x;
  const int dir = bx & 1, bg = (bx >> 1) & 3, ks = (bx >> 3) & 3, jt = bx >> 5;
  const int jj = jt*256 + tid;
  const float* Wd = WhT + (long)dir*HENC*G3E;
  __shared__ float hsm[4][128];
  int epoch = 0;
  // phase2 thread mapping (fixed across steps)
  const int t2 = bx*256 + tid;
  const int d2 = t2 >> 13, r2 = t2 & 8191, b2 = r2 >> 9, j2 = r2 & 511;
  const float* GX2 = d2 ? GXb : GXf;
  const float bh0v = bh[d2*G3E + j2];
  const float bh1v = bh[d2*G3E + 512 + j2];
  const float bh2v = bh[d2*G3E + 1024 + j2];
  for (int s = 0; s < TSN; ++s) {
    const int cur = s & 1;
    // ---- phase 1: partial gh ----
    {
      #pragma unroll
      for (int i = 0; i < 2; ++i) {
        int li = tid + i*256;
        int bb = li >> 7, kk = li & 127;
        hsm[bb][kk] = hbuf[((dir*2 + cur)*NB + bg*4 + bb)*HENC + ks*128 + kk];
      }
      __syncthreads();
      float a0=0,a1=0,a2=0,a3=0, e0=0,e1=0,e2=0,e3=0, c0=0,c1=0,c2=0,c3=0;
      const float* wr = Wd + (long)(ks*128)*G3E + jj;
      for (int kk = 0; kk < 128; ++kk) {
        float w0 = wr[0], w1 = wr[512], w2 = wr[1024];
        wr += G3E;
        float h0v = hsm[0][kk], h1v = hsm[1][kk], h2v = hsm[2][kk], h3v = hsm[3][kk];
        a0 += h0v*w0; a1 += h1v*w0; a2 += h2v*w0; a3 += h3v*w0;
        e0 += h0v*w1; e1 += h1v*w1; e2 += h2v*w1; e3 += h3v*w1;
        c0 += h0v*w2; c1 += h1v*w2; c2 += h2v*w2; c3 += h3v*w2;
      }
      float* gp = ghp + ((long)(ks*2 + dir)*NB + bg*4)*G3E + jj;
      gp[0]            = a0; gp[G3E]            = a1; gp[2*G3E]            = a2; gp[3*G3E]            = a3;
      gp[512]          = e0; gp[G3E + 512]      = e1; gp[2*G3E + 512]      = e2; gp[3*G3E + 512]      = e3;
      gp[1024]         = c0; gp[G3E + 1024]     = c1; gp[2*G3E + 1024]     = c2; gp[3*G3E + 1024]     = c3;
    }
    gridbar(bar, 64, ++epoch);
    // ---- phase 2: gate combine ----
    {
      const int t = d2 ? (TSN - 1 - s) : s;
      float g0 = bh0v, g1 = bh1v, g2 = bh2v;
      #pragma unroll
      for (int kq = 0; kq < 4; ++kq) {
        const float* p = ghp + ((long)(kq*2 + d2)*NB + b2)*G3E;
        g0 += p[j2]; g1 += p[512 + j2]; g2 += p[1024 + j2];
      }
      const float* gx = GX2 + ((long)t*NB + b2)*G3E;
      float rr = 1.f/(1.f + expf(-(gx[j2] + g0)));
      float zz = 1.f/(1.f + expf(-(gx[512 + j2] + g1)));
      float nn = tanhf(gx[1024 + j2] + rr*g2);
      float hp = hbuf[((d2*2 + cur)*NB + b2)*HENC + j2];
      float hn = (1.f - zz)*nn + zz*hp;
      hbuf[((d2*2 + (cur^1))*NB + b2)*HENC + j2] = hn;
      Y[((long)t*NB + b2)*HD2 + d2*HENC + j2] = hn;
      if (s == TSN - 1) hfin[b2*HD2 + d2*HENC + j2] = hn;
    }
    gridbar(bar, 64, ++epoch);
  }
}

// ---------------- time-major -> batch-major copy ----------------
__global__ __launch_bounds__(256) void k_copy_tb(const float* __restrict__ Y, float* __restrict__ O)
{
  long i = (long)blockIdx.x*256 + threadIdx.x;
  if (i >= (long)TSN*NB*HD2) return;
  int d = (int)(i & (HD2 - 1));
  long r = i >> 10;
  int b = (int)(r % NB);
  int t = (int)(r / NB);
  O[((long)b*TSN + t)*HD2 + d] = Y[i];
}

// ---------------- row softmax, in place ----------------
__global__ __launch_bounds__(256) void k_softmax(float* __restrict__ X, int C)
{
  float* x = X + (long)blockIdx.x * C;
  int tid = threadIdx.x;
  __shared__ float red[256];
  float m = -INFINITY;
  for (int i = tid; i < C; i += 256) m = fmaxf(m, x[i]);
  red[tid] = m; __syncthreads();
  for (int o = 128; o; o >>= 1) { if (tid < o) red[tid] = fmaxf(red[tid], red[tid+o]); __syncthreads(); }
  m = red[0]; __syncthreads();
  float s = 0.f;
  for (int i = tid; i < C; i += 256) { float e = expf(x[i] - m); x[i] = e; s += e; }
  red[tid] = s; __syncthreads();
  for (int o = 128; o; o >>= 1) { if (tid < o) red[tid] += red[tid+o]; __syncthreads(); }
  float inv = 1.f/red[0];
  for (int i = tid; i < C; i += 256) x[i] *= inv;
}

// ---------------- self_out = g*f + (1-g)*o   (into f) ----------------
__global__ __launch_bounds__(256) void k_selfcomb(
    float* __restrict__ f, const float* __restrict__ g, const float* __restrict__ o, long n)
{
  long i = (long)blockIdx.x*256 + threadIdx.x;
  if (i >= n) return;
  float gg = g[i];
  f[i] = gg*f[i] + (1.f - gg)*o[i];
}

// ---------------- answer attention (softmax over t per (b,d)) + enc_out ----------------
__global__ __launch_bounds__(256) void k_ansatt(
    const float* __restrict__ mem, const float* __restrict__ selfo,
    const int* __restrict__ input_a, float* __restrict__ enc_out)
{
  int b = blockIdx.x >> 2;
  int d = (blockIdx.x & 3)*256 + threadIdx.x;
  float m = -INFINITY;
  for (int t = 0; t < TSN; ++t) {
    float v = mem[((long)b*TSN + t)*HD2 + d];
    float e = input_a[b*TSN + t] ? v*v : v;
    m = fmaxf(m, e);
  }
  float s = 0.f;
  for (int t = 0; t < TSN; ++t) {
    float v = mem[((long)b*TSN + t)*HD2 + d];
    float e = input_a[b*TSN + t] ? v*v : v;
    s += expf(e - m);
  }
  float inv = 1.f/s;
  for (int t = 0; t < TSN; ++t) {
    long idx = ((long)b*TSN + t)*HD2 + d;
    float v = mem[idx];
    float e = input_a[b*TSN + t] ? v*v : v;
    enc_out[idx] = selfo[idx] + expf(e - m)*inv*v;
  }
}

// ---------------- skinny GEMM: P[ks][16][N] = A[16, kchunk] * W^T  (K chunk = 256) ----------------
__global__ __launch_bounds__(256) void k_sgemm16(
    const float* __restrict__ A, int lda,
    const float* __restrict__ W, int ldw,
    float* __restrict__ P, int N)
{
  __shared__ float As[16][65];
  __shared__ float Ws[64][65];
  const int n0 = blockIdx.x*64;
  const int ksb = blockIdx.y;
  const int k0 = ksb*256;
  const int tid = threadIdx.x;
  const int nl = tid & 63, bg = tid >> 6;
  float acc[4] = {};
  for (int kc = 0; kc < 256; kc += 64) {
    __syncthreads();
    #pragma unroll
    for (int i = 0; i < 4; ++i) {
      int li = tid + i*256; int r = li >> 6, c = li & 63;
      As[r][c] = A[(long)r*lda + k0 + kc + c];
    }
    #pragma unroll
    for (int i = 0; i < 16; ++i) {
      int li = tid + i*256; int r = li >> 6, c = li & 63;
      Ws[r][c] = W[(long)(n0 + r)*ldw + k0 + kc + c];
    }
    __syncthreads();
    #pragma unroll 4
    for (int k = 0; k < 64; ++k) {
      float w = Ws[nl][k];
      acc[0] += As[bg*4 + 0][k]*w;
      acc[1] += As[bg*4 + 1][k]*w;
      acc[2] += As[bg*4 + 2][k]*w;
      acc[3] += As[bg*4 + 3][k]*w;
    }
  }
  #pragma unroll
  for (int bb = 0; bb < 4; ++bb)
    P[((long)ksb*NB + bg*4 + bb)*N + n0 + nl] = acc[bb];
}

// ---------------- decoder GRU gate combine ----------------
__global__ __launch_bounds__(256) void k_comb_gru(
    const float* __restrict__ Pgx, int nsx,
    const float* __restrict__ gxA, const float* __restrict__ gxb,
    const float* __restrict__ Pgh, int nsh,
    const float* __restrict__ bh,
    const float* __restrict__ hprev, float* __restrict__ hout, float* __restrict__ hout2)
{
  int t = blockIdx.x*256 + threadIdx.x;   // 16384
  int b = t >> 10, j = t & 1023;
  float gx[3], gh[3];
  #pragma unroll
  for (int g = 0; g < 3; ++g) {
    int col = g*HD2 + j;
    float sx = gxA ? gxA[(long)b*G3D + col] : 0.f;
    for (int ks = 0; ks < nsx; ++ks) sx += Pgx[((long)ks*NB + b)*G3D + col];
    if (gxb) sx += gxb[col];
    gx[g] = sx;
    float sh = bh[col];
    for (int ks = 0; ks < nsh; ++ks) sh += Pgh[((long)ks*NB + b)*G3D + col];
    gh[g] = sh;
  }
  float rr = 1.f/(1.f + expf(-(gx[0] + gh[0])));
  float zz = 1.f/(1.f + expf(-(gx[1] + gh[1])));
  float nn = tanhf(gx[2] + rr*gh[2]);
  float hp = hprev[t];
  float hn = (1.f - zz)*nn + zz*hp;
  hout[t] = hn;
  if (hout2) hout2[(long)b*2048 + j] = hn;
}

// ---------------- decoder attention: energy, cov softmax, cov update, cov_loss ----------------
__global__ __launch_bounds__(256) void k_dec_attn(
    const float* __restrict__ h1, const float* __restrict__ memd,
    float* __restrict__ cov, float* __restrict__ attnb,
    float* __restrict__ cove, float* __restrict__ covacc)
{
  int b = blockIdx.x, tid = threadIdx.x;
  __shared__ float hs[1024];
  __shared__ float sc[TSN];
  __shared__ float red[256];
  for (int i = tid; i < 1024; i += 256) hs[i] = h1[b*1024 + i];
  __syncthreads();
  int wv = tid >> 6, ln = tid & 63;
  for (int t = wv; t < TSN; t += 4) {
    const float* row = memd + ((long)b*TSN + t)*HD2;
    float p = 0.f;
    #pragma unroll
    for (int i = 0; i < 16; ++i) p += hs[i*64 + ln]*row[i*64 + ln];
    #pragma unroll
    for (int off = 32; off; off >>= 1) p += __shfl_xor(p, off);
    if (ln == 0) sc[t] = p;
  }
  __syncthreads();
  float ce[2], co[2];
  #pragma unroll
  for (int i = 0; i < 2; ++i) {
    int t = tid + i*256;
    ce[i] = -INFINITY; co[i] = 0.f;
    if (t < TSN) { co[i] = cov[b*TSN + t]; ce[i] = sc[t]*(1.f - co[i]); }
  }
  float m = fmaxf(ce[0], ce[1]);
  red[tid] = m; __syncthreads();
  for (int o = 128; o; o >>= 1) { if (tid < o) red[tid] = fmaxf(red[tid], red[tid+o]); __syncthreads(); }
  m = red[0]; __syncthreads();
  float ex[2]; float ssum = 0.f;
  #pragma unroll
  for (int i = 0; i < 2; ++i) {
    int t = tid + i*256; ex[i] = 0.f;
    if (t < TSN) { ex[i] = expf(ce[i] - m); ssum += ex[i]; }
  }
  red[tid] = ssum; __syncthreads();
  for (int o = 128; o; o >>= 1) { if (tid < o) red[tid] += red[tid+o]; __syncthreads(); }
  float inv = 1.f/red[0]; __syncthreads();
  float closs = 0.f;
  #pragma unroll
  for (int i = 0; i < 2; ++i) {
    int t = tid + i*256;
    if (t < TSN) {
      float a = ex[i]*inv;
      attnb[b*TSN + t] = a;
      cove[b*TSN + t]  = ce[i];
      cov[b*TSN + t]   = co[i] + a;
      closs += fminf(a, co[i]);
    }
  }
  red[tid] = closs; __syncthreads();
  for (int o = 128; o; o >>= 1) { if (tid < o) red[tid] += red[tid+o]; __syncthreads(); }
  if (tid == 0) atomicAdd(covacc, red[0]);
}

// ---------------- new_ctx = attn @ mem_d ; also fills cat[:,1024:] ----------------
__global__ __launch_bounds__(256) void k_dec_ctx(
    const float* __restrict__ attnb, const float* __restrict__ memd,
    float* __restrict__ ctxn, float* __restrict__ cat)
{
  int b = blockIdx.x >> 2;
  int d = (blockIdx.x & 3)*256 + threadIdx.x;
  __shared__ float at[TSN];
  for (int i = threadIdx.x; i < TSN; i += 256) at[i] = attnb[b*TSN + i];
  __syncthreads();
  float s = 0.f;
  for (int t = 0; t < TSN; ++t) s += at[t]*memd[((long)b*TSN + t)*HD2 + d];
  ctxn[b*HD2 + d] = s;
  cat[(long)b*2048 + 1024 + d] = s;
}

// ---------------- scatter-max of cov_e into ubuf (order-preserving uint encode) ----------------
__device__ __forceinline__ unsigned enc_f(float f) {
  unsigned b = __float_as_uint(f);
  return (b & 0x80000000u) ? ~b : (b | 0x80000000u);
}
__device__ __forceinline__ float dec_f(unsigned e) {
  return (e & 0x80000000u) ? __uint_as_float(e ^ 0x80000000u) : __uint_as_float(~e);
}
__global__ __launch_bounds__(256) void k_scatter(
    const int* __restrict__ ids, const float* __restrict__ cove, unsigned* __restrict__ ubuf)
{
  int i = blockIdx.x*256 + threadIdx.x;
  if (i >= NB*TSN) return;
  int b = i / TSN;
  atomicMax(&ubuf[(long)b*NEXT + ids[i]], enc_f(cove[i]));
}
__global__ __launch_bounds__(256) void k_clear(
    const int* __restrict__ ids, unsigned* __restrict__ ubuf)
{
  int i = blockIdx.x*256 + threadIdx.x;
  if (i >= NB*TSN) return;
  int b = i / TSN;
  ubuf[(long)b*NEXT + ids[i]] = 0u;
}

// ---------------- hid = tanh(sum of 8 partials + pb1) ----------------
__global__ __launch_bounds__(256) void k_comb_hid(
    const float* __restrict__ P, const float* __restrict__ pb1, float* __restrict__ hid)
{
  int t = blockIdx.x*256 + threadIdx.x;   // 16384
  int b = t >> 10, j = t & 1023;
  float s = pb1[j];
  #pragma unroll
  for (int ks = 0; ks < 8; ++ks) s += P[((long)ks*NB + b)*HD2 + j];
  hid[t] = tanhf(s);
}

// ---------------- logits + ext/copy compose, writes d_out slab for step s ----------------
__global__ __launch_bounds__(256) void k_logits(
    const float* __restrict__ hid, const float* __restrict__ pW2,
    const float* __restrict__ pb2, const unsigned* __restrict__ ubuf,
    float* __restrict__ outp, int s)
{
  const int v0 = blockIdx.x*128;
  const int tid = threadIdx.x;
  const int vl = tid & 127, bh = tid >> 7;
  __shared__ float hs[16][256];
  __shared__ float Ws[128][65];
  float acc[8] = {};
  for (int k0 = 0; k0 < 1024; k0 += 256) {
    __syncthreads();
    #pragma unroll
    for (int i = 0; i < 16; ++i) {
      int li = tid + i*256; int r = li >> 8, c = li & 255;
      hs[r][c] = hid[r*1024 + k0 + c];
    }
    for (int k1 = 0; k1 < 256; k1 += 64) {
      __syncthreads();
      #pragma unroll
      for (int i = 0; i < 32; ++i) {
        int li = tid + i*256; int r = li >> 6, c = li & 63;
        int v = v0 + r;
        Ws[r][c] = (v < NV) ? pW2[(long)v*1024 + k0 + k1 + c] : 0.f;
      }
      __syncthreads();
      #pragma unroll 4
      for (int k = 0; k < 64; ++k) {
        float w = Ws[vl][k];
        #pragma unroll
        for (int bb = 0; bb < 8; ++bb) acc[bb] += hs[bh*8 + bb][k1 + k]*w;
      }
    }
  }
  const int v = v0 + vl;
  if (v >= NEXT) return;
  #pragma unroll
  for (int bb = 0; bb < 8; ++bb) {
    int b = bh*8 + bb;
    unsigned u = ubuf[(long)b*NEXT + v];
    float o = u ? dec_f(u) : 0.f;
    float e = (v < NV) ? (acc[bb] + pb2[v]) : 0.f;
    float lg = e + o;
    if (lg == 0.f) lg = NEG_INF;
    outp[((long)b*NTT + s)*NEXT + v] = lg;
  }
}

// ---------------- final coverage-loss scalar ----------------
__global__ void k_covout(const float* __restrict__ covacc, float* __restrict__ outp)
{
  outp[(long)NB*NTT*NEXT] = covacc[0] * (1.0f/(NB*NTT));
}

// ==================== host ====================
extern "C" void kernel_launch(void* const* d_in, const int* in_sizes, int n_in,
                              void* d_out, int out_size, void* d_ws, size_t ws_size,
                              hipStream_t stream) {
  (void)in_sizes; (void)n_in; (void)out_size; (void)ws_size;
  const float* enc_emb = (const float*)d_in[0];
  const float* ans_emb = (const float*)d_in[1];
  const float* dec_emb = (const float*)d_in[2];
  const float* eWi0 = (const float*)d_in[3];
  const float* eWh0 = (const float*)d_in[4];
  const float* ebi0 = (const float*)d_in[5];
  const float* ebh0 = (const float*)d_in[6];
  const float* eWi1 = (const float*)d_in[7];
  const float* eWh1 = (const float*)d_in[8];
  const float* ebi1 = (const float*)d_in[9];
  const float* ebh1 = (const float*)d_in[10];
  const float* trans_W = (const float*)d_in[11];
  const float* trans_b = (const float*)d_in[12];
  const float* upd_W = (const float*)d_in[13];
  const float* gate_W = (const float*)d_in[14];
  const float* dWi0 = (const float*)d_in[15];
  const float* dWh0 = (const float*)d_in[16];
  const float* dbi0 = (const float*)d_in[17];
  const float* dbh0 = (const float*)d_in[18];
  const float* dWi1 = (const float*)d_in[19];
  const float* dWh1 = (const float*)d_in[20];
  const float* dbi1 = (const float*)d_in[21];
  const float* dbh1 = (const float*)d_in[22];
  const float* dtrans_W = (const float*)d_in[23];
  const float* dtrans_b = (const float*)d_in[24];
  const float* pW1 = (const float*)d_in[25];
  const float* pb1 = (const float*)d_in[26];
  const float* pW2 = (const float*)d_in[27];
  const float* pb2 = (const float*)d_in[28];
  const int* input_s = (const int*)d_in[29];
  const int* ext_ids = (const int*)d_in[30];
  const int* input_q = (const int*)d_in[31];
  const int* input_a = (const int*)d_in[32];
  float* out = (float*)d_out;

  float* ws = (float*)d_ws;
  size_t off = 0;
  auto alloc = [&](size_t n) { float* p = ws + off; off += n; return p; };
  float* X0    = alloc(6400ull*IN0);
  float* GXf   = alloc(6400ull*G3E);
  float* GXb   = alloc(6400ull*G3E);
  float* Y0    = alloc(6400ull*HD2);
  float* Y1    = alloc(6400ull*HD2);
  float* WhT0  = alloc(2ull*HENC*G3E);
  float* WhT1  = alloc(2ull*HENC*G3E);
  float* hbuf  = alloc(2ull*2*NB*HENC);
  float* ghp   = alloc(4ull*2*NB*G3E);
  float* hfin0 = alloc(NB*HD2);
  float* hfin1 = alloc(NB*HD2);
  int*   bar   = (int*)alloc(16);
  float* outp  = alloc(6400ull*HD2);
  float* mems  = alloc(6400ull*HD2);
  float* energ = alloc((size_t)NB*TSN*TSN);
  float* ctxb  = alloc(6400ull*HD2);
  float* ft    = alloc(6400ull*HD2);
  float* gt    = alloc(6400ull*HD2);
  float* memd  = alloc(6400ull*HD2);
  float* embq  = alloc((size_t)NTT*NB*EMBD);
  float* embGX = alloc((size_t)NTT*NB*G3D);
  float* dh0   = alloc(2ull*NB*HD2);
  float* dh1   = alloc(2ull*NB*HD2);
  float* dctx  = alloc(2ull*NB*HD2);
  float* cov   = alloc(NB*TSN);
  float* attnb = alloc(NB*TSN);
  float* cove  = alloc(NB*TSN);
  float* cat   = alloc(NB*2048);
  float* p_gxc = alloc(4ull*NB*G3D);
  float* p_gh0 = alloc(4ull*NB*G3D);
  float* p_gx1 = alloc(4ull*NB*G3D);
  float* p_gh1 = alloc(4ull*NB*G3D);
  float* p_hid = alloc(8ull*NB*HD2);
  float* hid   = alloc(NB*HD2);
  unsigned* ubuf = (unsigned*)alloc((size_t)NB*NEXT);
  float* covacc = alloc(4);

  // ---------------- encoder ----------------
  k_embed<<<8300, 256, 0, stream>>>(enc_emb, ans_emb, input_s, input_a, X0);

  k_transpose<<<dim3(48,16), 256, 0, stream>>>(eWh0,             WhT0,             G3E, HENC, HENC);
  k_transpose<<<dim3(48,16), 256, 0, stream>>>(eWh0 + G3E*HENC,  WhT0 + HENC*G3E,  G3E, HENC, HENC);
  k_transpose<<<dim3(48,16), 256, 0, stream>>>(eWh1,             WhT1,             G3E, HENC, HENC);
  k_transpose<<<dim3(48,16), 256, 0, stream>>>(eWh1 + G3E*HENC,  WhT1 + HENC*G3E,  G3E, HENC, HENC);

  // layer 0 gx
  k_gemm_nt<<<dim3(100,24,1), 256, 0, stream>>>(X0, eWi0,            ebi0,        GXf, 6400, G3E, IN0, IN0, IN0, G3E, 0,0,0, 0, 0);
  k_gemm_nt<<<dim3(100,24,1), 256, 0, stream>>>(X0, eWi0 + G3E*IN0,  ebi0 + G3E,  GXb, 6400, G3E, IN0, IN0, IN0, G3E, 0,0,0, 0, 0);
  hipMemsetAsync(hbuf, 0, 2ull*2*NB*HENC*4, stream);
  hipMemsetAsync(bar, 0, 16, stream);
  k_scan<<<64, 256, 0, stream>>>(GXf, GXb, WhT0, ebh0, Y0, hfin0, hbuf, ghp, bar);
  // layer 1 gx
  k_gemm_nt<<<dim3(100,24,1), 256, 0, stream>>>(Y0, eWi1,            ebi1,        GXf, 6400, G3E, HD2, HD2, HD2, G3E, 0,0,0, 0, 0);
  k_gemm_nt<<<dim3(100,24,1), 256, 0, stream>>>(Y0, eWi1 + G3E*HD2,  ebi1 + G3E,  GXb, 6400, G3E, HD2, HD2, HD2, G3E, 0,0,0, 0, 0);
  hipMemsetAsync(hbuf, 0, 2ull*2*NB*HENC*4, stream);
  hipMemsetAsync(bar, 0, 16, stream);
  k_scan<<<64, 256, 0, stream>>>(GXf, GXb, WhT1, ebh1, Y1, hfin1, hbuf, ghp, bar);

  k_copy_tb<<<25600, 256, 0, stream>>>(Y1, outp);
  // memories
  k_gemm_nt<<<dim3(100,16,1), 256, 0, stream>>>(outp, trans_W, trans_b, mems, 6400, HD2, HD2, HD2, HD2, HD2, 0,0,0, 0, 0);
  // self attention
  k_gemm_nt<<<dim3(7,7,16), 256, 0, stream>>>(outp, mems, nullptr, energ, TSN, TSN, HD2, HD2, HD2, TSN,
                                              (long)TSN*HD2, (long)TSN*HD2, (long)TSN*TSN, 0, 0);
  k_softmax<<<NB*TSN, 256, 0, stream>>>(energ, TSN);
  k_gemm_nn<<<dim3(7,16,16), 256, 0, stream>>>(energ, outp, ctxb, TSN, HD2, TSN, TSN, HD2, HD2,
                                               (long)TSN*TSN, (long)TSN*HD2, (long)TSN*HD2);
  // f_t / g_t (split-K accumulate, activation on 2nd call)
  k_gemm_nt<<<dim3(100,16,1), 256, 0, stream>>>(outp, upd_W,        nullptr, ft, 6400, HD2, HD2, HD2, 2048, HD2, 0,0,0, 0, 0);
  k_gemm_nt<<<dim3(100,16,1), 256, 0, stream>>>(ctxb, upd_W + HD2,  nullptr, ft, 6400, HD2, HD2, HD2, 2048, HD2, 0,0,0, 1, 1);
  k_gemm_nt<<<dim3(100,16,1), 256, 0, stream>>>(outp, gate_W,       nullptr, gt, 6400, HD2, HD2, HD2, 2048, HD2, 0,0,0, 0, 0);
  k_gemm_nt<<<dim3(100,16,1), 256, 0, stream>>>(ctxb, gate_W + HD2, nullptr, gt, 6400, HD2, HD2, HD2, 2048, HD2, 0,0,0, 1, 2);
  k_selfcomb<<<25600, 256, 0, stream>>>(ft, gt, outp, 6553600L);
  k_ansatt<<<64, 256, 0, stream>>>(mems, ft, input_a, gt);   // enc_out -> gt
  // mem_d
  k_gemm_nt<<<dim3(100,16,1), 256, 0, stream>>>(gt, dtrans_W, dtrans_b, memd, 6400, HD2, HD2, HD2, HD2, HD2, 0,0,0, 0, 0);

  // ---------------- decoder precompute ----------------
  k_embq<<<600, 256, 0, stream>>>(dec_emb, input_q, embq);
  k_gemm_nt<<<dim3(8,48,1), 256, 0, stream>>>(embq, dWi0, dbi0, embGX, NTT*NB, G3D, EMBD, EMBD, 1324, G3D, 0,0,0, 0, 0);

  hipMemsetAsync(cov, 0, (size_t)NB*TSN*4, stream);
  hipMemsetAsync(dctx, 0, 2ull*NB*HD2*4, stream);
  hipMemsetAsync(covacc, 0, 4, stream);
  hipMemsetAsync(ubuf, 0, (size_t)NB*NEXT*4, stream);
  hipMemcpyAsync(dh0, hfin0, (size_t)NB*HD2*4, hipMemcpyDeviceToDevice, stream);
  hipMemcpyAsync(dh1, hfin1, (size_t)NB*HD2*4, hipMemcpyDeviceToDevice, stream);

  // ---------------- decoder steps ----------------
  for (int s = 0; s < NTT; ++s) {
    int cur = s & 1, nxt = cur ^ 1;
    float* h0c = dh0 + (size_t)cur*NB*HD2;  float* h0n = dh0 + (size_t)nxt*NB*HD2;
    float* h1c = dh1 + (size_t)cur*NB*HD2;  float* h1n = dh1 + (size_t)nxt*NB*HD2;
    float* ctxc = dctx + (size_t)cur*NB*HD2; float* ctxn = dctx + (size_t)nxt*NB*HD2;

    k_sgemm16<<<dim3(48,4), 256, 0, stream>>>(ctxc, HD2, dWi0 + 300, 1324, p_gxc, G3D);
    k_sgemm16<<<dim3(48,4), 256, 0, stream>>>(h0c,  HD2, dWh0,       HD2,  p_gh0, G3D);
    k_comb_gru<<<64, 256, 0, stream>>>(p_gxc, 4, embGX + (size_t)s*NB*G3D, nullptr, p_gh0, 4, dbh0, h0c, h0n, nullptr);
    k_sgemm16<<<dim3(48,4), 256, 0, stream>>>(h0n, HD2, dWi1, HD2, p_gx1, G3D);
    k_sgemm16<<<dim3(48,4), 256, 0, stream>>>(h1c, HD2, dWh1, HD2, p_gh1, G3D);
    k_comb_gru<<<64, 256, 0, stream>>>(p_gx1, 4, nullptr, dbi1, p_gh1, 4, dbh1, h1c, h1n, cat);
    k_dec_attn<<<NB, 256, 0, stream>>>(h1n, memd, cov, attnb, cove, covacc);
    k_dec_ctx<<<64, 256, 0, stream>>>(attnb, memd, ctxn, cat);
    k_scatter<<<25, 256, 0, stream>>>(ext_ids, cove, ubuf);
    k_sgemm16<<<dim3(16,8), 256, 0, stream>>>(cat, 2048, pW1, 2048, p_hid, HD2);
    k_comb_hid<<<64, 256, 0, stream>>>(p_hid, pb1, hid);
    k_logits<<<392, 256, 0, stream>>>(hid, pW2, pb2, ubuf, out, s);
    k_clear<<<25, 256, 0, stream>>>(ext_ids, ubuf);
  }
  k_covout<<<1, 1, 0, stream>>>(covacc, out);
}

// Round 2
// 23826.349 us; speedup vs baseline: 1.6714x; 1.6714x over previous
//
#include <hip/hip_runtime.h>
#include <stdint.h>

#define TSN 400
#define NB 16
#define HENC 512
#define HD2 1024
#define G3E 1536
#define G3D 3072
#define EMBD 300
#define AEMB 32
#define NV 50000
#define NEXT 50100
#define NVP 50176
#define NTT 32
#define NEG_INF (-1.0e12f)

typedef __attribute__((ext_vector_type(8))) short bf16x8;
typedef __attribute__((ext_vector_type(4))) float f32x4;

__device__ __forceinline__ ushort f2bf(float f) {
  unsigned u = __float_as_uint(f);
  unsigned r = (u + 0x7fffu + ((u >> 16) & 1u)) >> 16;
  return (ushort)r;
}
__device__ __forceinline__ float bf2f(ushort h) {
  return __uint_as_float((unsigned)h << 16);
}

// ---------------- device-scope grid barrier ----------------
__device__ __forceinline__ void gridbar(int* bar, int nblocks, int epoch) {
  __syncthreads();
  if (threadIdx.x == 0) {
    __threadfence();
    __hip_atomic_fetch_add(bar, 1, __ATOMIC_ACQ_REL, __HIP_MEMORY_SCOPE_AGENT);
    const int target = nblocks * epoch;
    while (__hip_atomic_load(bar, __ATOMIC_ACQUIRE, __HIP_MEMORY_SCOPE_AGENT) < target)
      __builtin_amdgcn_s_sleep(2);
    __threadfence();
  }
  __syncthreads();
}

// ---------------- embeddings -> bf16, padded K=384 ----------------
__global__ __launch_bounds__(256) void k_embed_bf(
    const float* __restrict__ enc_emb, const float* __restrict__ ans_emb,
    const int* __restrict__ input_s, const int* __restrict__ input_a,
    ushort* __restrict__ X0)
{
  long i = (long)blockIdx.x*256 + threadIdx.x;
  if (i >= (long)TSN*NB*384) return;
  int c = (int)(i % 384);
  long r = i / 384;
  int b = (int)(r % NB);
  int t = (int)(r / NB);
  float v = 0.f;
  if (c < EMBD) v = enc_emb[(long)input_s[b*TSN + t]*EMBD + c];
  else if (c < 332) v = ans_emb[(long)input_a[b*TSN + t]*AEMB + (c - EMBD)];
  X0[i] = f2bf(v);
}

// ---------------- decoder emb -> bf16, padded K=320 ----------------
__global__ __launch_bounds__(256) void k_embq_bf(
    const float* __restrict__ dec_emb, const int* __restrict__ input_q,
    ushort* __restrict__ EQ)
{
  long i = (long)blockIdx.x*256 + threadIdx.x;
  if (i >= (long)NTT*NB*320) return;
  int c = (int)(i % 320);
  long r = i / 320;
  int b = (int)(r % NB);
  int s = (int)(r / NB);
  EQ[i] = (c < EMBD) ? f2bf(dec_emb[(long)input_q[b*33 + s]*EMBD + c]) : (ushort)0;
}

// ---------------- weight cast with pad: dst[n][k] (n<Nsrc,k<Ksrc -> src else 0) ----------------
__global__ __launch_bounds__(256) void k_castw(
    const float* __restrict__ src, ushort* __restrict__ dst,
    int Nsrc, long total, int Ksrc, int Kdst, int ldsrc, int coloff)
{
  long i = (long)blockIdx.x*256 + threadIdx.x;
  if (i >= total) return;
  int k = (int)(i % Kdst);
  long n = i / Kdst;
  float v = (n < Nsrc && k < Ksrc) ? src[n*ldsrc + coloff + k] : 0.f;
  dst[i] = f2bf(v);
}

// ---------------- plain cast fp32 -> bf16 ----------------
__global__ __launch_bounds__(256) void k_cast(
    const float* __restrict__ s, ushort* __restrict__ d, long n)
{
  long i = (long)blockIdx.x*256 + threadIdx.x;
  if (i >= n) return;
  d[i] = f2bf(s[i]);
}

// ---------------- transpose+cast: out[c][r] = in[r][c]  (bf16 out) ----------------
__global__ __launch_bounds__(256) void k_transpose_bf(
    const float* __restrict__ in, ushort* __restrict__ out, int R, int C, int ldin)
{
  __shared__ float tbuf[32][33];
  int r0 = blockIdx.x*32, c0 = blockIdx.y*32;
  int tx = threadIdx.x & 31, ty = threadIdx.x >> 5;
  #pragma unroll
  for (int i = 0; i < 32; i += 8) {
    int r = r0 + ty + i, c = c0 + tx;
    tbuf[ty+i][tx] = (r < R && c < C) ? in[(long)r*ldin + c] : 0.f;
  }
  __syncthreads();
  #pragma unroll
  for (int i = 0; i < 32; i += 8) {
    int c = c0 + ty + i, r = r0 + tx;
    if (c < C && r < R) out[(long)c*R + r] = f2bf(tbuf[tx][ty+i]);
  }
}

// ---------------- MFMA GEMM: C = act((accum?C:0) + A[M,K]bf16 * W[N,K]bf16^T + bias) ----------------
// 64x64 tile, BK=64, 4 waves 2x2, each wave 32x32. K%64==0 required.
__global__ __launch_bounds__(256) void k_mfma_nt(
    const ushort* __restrict__ Ab, const ushort* __restrict__ Wb,
    const float* __restrict__ bias, float* __restrict__ Cb, ushort* __restrict__ C2b,
    int M, int N, int K, int lda, int ldw, int ldc,
    long sA, long sW, long sC, long sBias, int accum, int act)
{
  __shared__ ushort As[64][72];
  __shared__ ushort Ws[64][72];
  const ushort* A = Ab + (long)blockIdx.z * sA;
  const ushort* W = Wb + (long)blockIdx.z * sW;
  float* C = Cb + (long)blockIdx.z * sC;
  const float* bi = bias ? bias + (long)blockIdx.z * sBias : nullptr;
  const int m0 = blockIdx.x*64, n0 = blockIdx.y*64;
  const int tid = threadIdx.x;
  const int wave = tid >> 6, lane = tid & 63;
  const int wm = wave >> 1, wn = wave & 1;
  const int lr = lane & 15, kg = lane >> 4;
  f32x4 acc[2][2] = {};
  for (int k0 = 0; k0 < K; k0 += 64) {
    __syncthreads();
    #pragma unroll
    for (int it = 0; it < 2; ++it) {
      int sidx = tid + it*256;
      int r = sidx >> 3, c = (sidx & 7)*8;
      bf16x8 av = {};
      bf16x8 wv = {};
      if (m0 + r < M) av = *(const bf16x8*)&A[(long)(m0+r)*lda + k0 + c];
      if (n0 + r < N) wv = *(const bf16x8*)&W[(long)(n0+r)*ldw + k0 + c];
      *(bf16x8*)&As[r][c] = av;
      *(bf16x8*)&Ws[r][c] = wv;
    }
    __syncthreads();
    #pragma unroll
    for (int kk = 0; kk < 2; ++kk) {
      bf16x8 af[2], bf[2];
      #pragma unroll
      for (int mt = 0; mt < 2; ++mt)
        af[mt] = *(const bf16x8*)&As[wm*32 + mt*16 + lr][kk*32 + kg*8];
      #pragma unroll
      for (int nt = 0; nt < 2; ++nt)
        bf[nt] = *(const bf16x8*)&Ws[wn*32 + nt*16 + lr][kk*32 + kg*8];
      #pragma unroll
      for (int mt = 0; mt < 2; ++mt)
        #pragma unroll
        for (int nt = 0; nt < 2; ++nt)
          acc[mt][nt] = __builtin_amdgcn_mfma_f32_16x16x32_bf16(af[mt], bf[nt], acc[mt][nt], 0, 0, 0);
    }
  }
  #pragma unroll
  for (int mt = 0; mt < 2; ++mt) {
    #pragma unroll
    for (int r = 0; r < 4; ++r) {
      int m = m0 + wm*32 + mt*16 + kg*4 + r;
      if (m >= M) continue;
      #pragma unroll
      for (int nt = 0; nt < 2; ++nt) {
        int n = n0 + wn*32 + nt*16 + lr;
        if (n >= N) continue;
        float v = acc[mt][nt][r];
        if (accum) v += C[(long)m*ldc + n];
        if (bi)    v += bi[n];
        if (act == 1) v = tanhf(v);
        else if (act == 2) v = 1.f/(1.f + expf(-v));
        C[(long)m*ldc + n] = v;
        if (C2b) C2b[(long)blockIdx.z*sC + (long)m*ldc + n] = f2bf(v);
      }
    }
  }
}

// ---------------- skinny MFMA: P[16][N] = A[16][K]bf16 @ W[N][K]bf16^T (paired) ----------------
__global__ __launch_bounds__(256) void k_skinny(
    const ushort* __restrict__ A0, const ushort* __restrict__ W0, float* __restrict__ P0,
    const ushort* __restrict__ A1, const ushort* __restrict__ W1, float* __restrict__ P1,
    int N, int K)
{
  const ushort* A = blockIdx.y ? A1 : A0;
  const ushort* W = blockIdx.y ? W1 : W0;
  float* P = blockIdx.y ? P1 : P0;
  const int wave = threadIdx.x >> 6, lane = threadIdx.x & 63;
  const int lr = lane & 15, kg = lane >> 4;
  const int n0 = blockIdx.x*64 + wave*16;
  f32x4 acc = {};
  const ushort* arow = A + (long)lr*K + kg*8;
  const ushort* wrow = W + (long)(n0 + lr)*K + kg*8;
  for (int k0 = 0; k0 < K; k0 += 32) {
    bf16x8 af = *(const bf16x8*)(arow + k0);
    bf16x8 bf = *(const bf16x8*)(wrow + k0);
    acc = __builtin_amdgcn_mfma_f32_16x16x32_bf16(af, bf, acc, 0, 0, 0);
  }
  #pragma unroll
  for (int r = 0; r < 4; ++r)
    P[(long)(kg*4 + r)*N + n0 + lr] = acc[r];
}

// ---------------- generic fp32 GEMM NN (kept for ctx = scores@output) ----------------
__global__ __launch_bounds__(256) void k_gemm_nn(
    const float* __restrict__ Ab, const float* __restrict__ Bb,
    float* __restrict__ Cb, int M, int N, int K,
    int lda, int ldb, int ldc, long sA, long sB, long sC)
{
  __shared__ float As[16][68];
  __shared__ float Bs[16][68];
  const float* A = Ab + (long)blockIdx.z * sA;
  const float* Bm = Bb + (long)blockIdx.z * sB;
  float* C = Cb + (long)blockIdx.z * sC;
  const int m0 = blockIdx.x*64, n0 = blockIdx.y*64;
  const int tid = threadIdx.x, tx = tid & 15, ty = tid >> 4;
  float acc[4][4] = {};
  for (int k0 = 0; k0 < K; k0 += 16) {
    #pragma unroll
    for (int i = 0; i < 4; ++i) {
      int li = tid + i*256;
      int r = li >> 4, c = li & 15;
      As[c][r] = (m0 + r < M && k0 + c < K) ? A[(long)(m0+r)*lda + k0 + c] : 0.f;
      int kk = li >> 6, nn = li & 63;
      Bs[kk][nn] = (k0 + kk < K && n0 + nn < N) ? Bm[(long)(k0+kk)*ldb + n0 + nn] : 0.f;
    }
    __syncthreads();
    #pragma unroll
    for (int k = 0; k < 16; ++k) {
      float4 av = *(const float4*)&As[k][ty*4];
      float4 bv = *(const float4*)&Bs[k][tx*4];
      acc[0][0] += av.x*bv.x; acc[0][1] += av.x*bv.y; acc[0][2] += av.x*bv.z; acc[0][3] += av.x*bv.w;
      acc[1][0] += av.y*bv.x; acc[1][1] += av.y*bv.y; acc[1][2] += av.y*bv.z; acc[1][3] += av.y*bv.w;
      acc[2][0] += av.z*bv.x; acc[2][1] += av.z*bv.y; acc[2][2] += av.z*bv.z; acc[2][3] += av.z*bv.w;
      acc[3][0] += av.w*bv.x; acc[3][1] += av.w*bv.y; acc[3][2] += av.w*bv.z; acc[3][3] += av.w*bv.w;
    }
    __syncthreads();
  }
  #pragma unroll
  for (int i = 0; i < 4; ++i) {
    int m = m0 + ty*4 + i;
    if (m >= M) continue;
    #pragma unroll
    for (int j = 0; j < 4; ++j) {
      int n = n0 + tx*4 + j;
      if (n >= N) continue;
      C[(long)m*ldc + n] = acc[i][j];
    }
  }
}

// ---------------- persistent bidirectional GRU scan (bf16 weights) ----------------
__global__ __launch_bounds__(256) void k_scan(
    const float* __restrict__ GXf, const float* __restrict__ GXb,
    const ushort* __restrict__ WhT,  // [2][512][1536] bf16
    const float* __restrict__ bh,
    float* __restrict__ Yf,          // optional fp32 out
    ushort* __restrict__ Ybf,        // optional bf16 out
    int bmajor,
    float* __restrict__ hfin,
    float* __restrict__ hbuf,
    float* __restrict__ ghp,
    int* __restrict__ bar)
{
  const int bx = blockIdx.x, tid = threadIdx.x;
  const int dir = bx & 1, bg = (bx >> 1) & 3, ks = (bx >> 3) & 3, jt = bx >> 5;
  const int jj = jt*256 + tid;
  const ushort* Wd = WhT + (long)dir*HENC*G3E;
  __shared__ float hsm[4][128];
  int epoch = 0;
  const int t2 = bx*256 + tid;
  const int d2 = t2 >> 13, r2 = t2 & 8191, b2 = r2 >> 9, j2 = r2 & 511;
  const float* GX2 = d2 ? GXb : GXf;
  const float bh0v = bh[d2*G3E + j2];
  const float bh1v = bh[d2*G3E + 512 + j2];
  const float bh2v = bh[d2*G3E + 1024 + j2];
  for (int s = 0; s < TSN; ++s) {
    const int cur = s & 1;
    {
      #pragma unroll
      for (int i = 0; i < 2; ++i) {
        int li = tid + i*256;
        int bb = li >> 7, kk = li & 127;
        hsm[bb][kk] = hbuf[((dir*2 + cur)*NB + bg*4 + bb)*HENC + ks*128 + kk];
      }
      __syncthreads();
      float a0=0,a1=0,a2=0,a3=0, e0=0,e1=0,e2=0,e3=0, c0=0,c1=0,c2=0,c3=0;
      const ushort* wr = Wd + (long)(ks*128)*G3E + jj;
      for (int kk = 0; kk < 128; ++kk) {
        float w0 = bf2f(wr[0]), w1 = bf2f(wr[512]), w2 = bf2f(wr[1024]);
        wr += G3E;
        float h0v = hsm[0][kk], h1v = hsm[1][kk], h2v = hsm[2][kk], h3v = hsm[3][kk];
        a0 += h0v*w0; a1 += h1v*w0; a2 += h2v*w0; a3 += h3v*w0;
        e0 += h0v*w1; e1 += h1v*w1; e2 += h2v*w1; e3 += h3v*w1;
        c0 += h0v*w2; c1 += h1v*w2; c2 += h2v*w2; c3 += h3v*w2;
      }
      float* gp = ghp + ((long)(ks*2 + dir)*NB + bg*4)*G3E + jj;
      gp[0]            = a0; gp[G3E]            = a1; gp[2*G3E]            = a2; gp[3*G3E]            = a3;
      gp[512]          = e0; gp[G3E + 512]      = e1; gp[2*G3E + 512]      = e2; gp[3*G3E + 512]      = e3;
      gp[1024]         = c0; gp[G3E + 1024]     = c1; gp[2*G3E + 1024]     = c2; gp[3*G3E + 1024]     = c3;
    }
    gridbar(bar, 64, ++epoch);
    {
      const int t = d2 ? (TSN - 1 - s) : s;
      float g0 = bh0v, g1 = bh1v, g2 = bh2v;
      #pragma unroll
      for (int kq = 0; kq < 4; ++kq) {
        const float* p = ghp + ((long)(kq*2 + d2)*NB + b2)*G3E;
        g0 += p[j2]; g1 += p[512 + j2]; g2 += p[1024 + j2];
      }
      const float* gx = GX2 + ((long)t*NB + b2)*G3E;
      float rr = 1.f/(1.f + expf(-(gx[j2] + g0)));
      float zz = 1.f/(1.f + expf(-(gx[512 + j2] + g1)));
      float nn = tanhf(gx[1024 + j2] + rr*g2);
      float hp = hbuf[((d2*2 + cur)*NB + b2)*HENC + j2];
      float hn = (1.f - zz)*nn + zz*hp;
      hbuf[((d2*2 + (cur^1))*NB + b2)*HENC + j2] = hn;
      long yidx = bmajor ? ((long)b2*TSN + t)*HD2 + d2*HENC + j2
                         : ((long)t*NB + b2)*HD2 + d2*HENC + j2;
      if (Yf)  Yf[yidx] = hn;
      if (Ybf) Ybf[yidx] = f2bf(hn);
      if (s == TSN - 1) hfin[b2*HD2 + d2*HENC + j2] = hn;
    }
    gridbar(bar, 64, ++epoch);
  }
}

// ---------------- row softmax, in place ----------------
__global__ __launch_bounds__(256) void k_softmax(float* __restrict__ X, int C)
{
  float* x = X + (long)blockIdx.x * C;
  int tid = threadIdx.x;
  __shared__ float red[256];
  float m = -INFINITY;
  for (int i = tid; i < C; i += 256) m = fmaxf(m, x[i]);
  red[tid] = m; __syncthreads();
  for (int o = 128; o; o >>= 1) { if (tid < o) red[tid] = fmaxf(red[tid], red[tid+o]); __syncthreads(); }
  m = red[0]; __syncthreads();
  float s = 0.f;
  for (int i = tid; i < C; i += 256) { float e = expf(x[i] - m); x[i] = e; s += e; }
  red[tid] = s; __syncthreads();
  for (int o = 128; o; o >>= 1) { if (tid < o) red[tid] += red[tid+o]; __syncthreads(); }
  float inv = 1.f/red[0];
  for (int i = tid; i < C; i += 256) x[i] *= inv;
}

// ---------------- self_out = g*f + (1-g)*o   (into f) ----------------
__global__ __launch_bounds__(256) void k_selfcomb(
    float* __restrict__ f, const float* __restrict__ g, const float* __restrict__ o, long n)
{
  long i = (long)blockIdx.x*256 + threadIdx.x;
  if (i >= n) return;
  float gg = g[i];
  f[i] = gg*f[i] + (1.f - gg)*o[i];
}

// ---------------- answer attention + enc_out ----------------
__global__ __launch_bounds__(256) void k_ansatt(
    const float* __restrict__ mem, const float* __restrict__ selfo,
    const int* __restrict__ input_a, float* __restrict__ enc_out)
{
  int b = blockIdx.x >> 2;
  int d = (blockIdx.x & 3)*256 + threadIdx.x;
  float m = -INFINITY;
  for (int t = 0; t < TSN; ++t) {
    float v = mem[((long)b*TSN + t)*HD2 + d];
    float e = input_a[b*TSN + t] ? v*v : v;
    m = fmaxf(m, e);
  }
  float s = 0.f;
  for (int t = 0; t < TSN; ++t) {
    float v = mem[((long)b*TSN + t)*HD2 + d];
    float e = input_a[b*TSN + t] ? v*v : v;
    s += expf(e - m);
  }
  float inv = 1.f/s;
  for (int t = 0; t < TSN; ++t) {
    long idx = ((long)b*TSN + t)*HD2 + d;
    float v = mem[idx];
    float e = input_a[b*TSN + t] ? v*v : v;
    enc_out[idx] = selfo[idx] + expf(e - m)*inv*v;
  }
}

// ---------------- decoder GRU combine ----------------
__global__ __launch_bounds__(256) void k_comb_gru2(
    const float* __restrict__ gx, const float* __restrict__ gxadd,
    const float* __restrict__ bi, const float* __restrict__ gh,
    const float* __restrict__ bh,
    const float* __restrict__ hprev, float* __restrict__ hout,
    ushort* __restrict__ hbfout, ushort* __restrict__ catbf)
{
  int t = blockIdx.x*256 + threadIdx.x;
  int b = t >> 10, j = t & 1023;
  float gxv[3], ghv[3];
  #pragma unroll
  for (int g = 0; g < 3; ++g) {
    int col = g*HD2 + j;
    float sx = gx[(long)b*G3D + col];
    if (gxadd) sx += gxadd[(long)b*G3D + col];
    if (bi)    sx += bi[col];
    gxv[g] = sx;
    ghv[g] = gh[(long)b*G3D + col] + bh[col];
  }
  float rr = 1.f/(1.f + expf(-(gxv[0] + ghv[0])));
  float zz = 1.f/(1.f + expf(-(gxv[1] + ghv[1])));
  float nn = tanhf(gxv[2] + rr*ghv[2]);
  float hp = hprev[t];
  float hn = (1.f - zz)*nn + zz*hp;
  hout[t] = hn;
  hbfout[t] = f2bf(hn);
  if (catbf) catbf[(long)b*2048 + j] = f2bf(hn);
}

// ---------------- decoder attention ----------------
__global__ __launch_bounds__(256) void k_dec_attn(
    const float* __restrict__ h1, const float* __restrict__ memd,
    float* __restrict__ cov, float* __restrict__ attnb,
    float* __restrict__ cove, float* __restrict__ covacc)
{
  int b = blockIdx.x, tid = threadIdx.x;
  __shared__ float hs[1024];
  __shared__ float sc[TSN];
  __shared__ float red[256];
  for (int i = tid; i < 1024; i += 256) hs[i] = h1[b*1024 + i];
  __syncthreads();
  int wv = tid >> 6, ln = tid & 63;
  for (int t = wv; t < TSN; t += 4) {
    const float* row = memd + ((long)b*TSN + t)*HD2;
    float p = 0.f;
    #pragma unroll
    for (int i = 0; i < 16; ++i) p += hs[i*64 + ln]*row[i*64 + ln];
    #pragma unroll
    for (int off = 32; off; off >>= 1) p += __shfl_xor(p, off);
    if (ln == 0) sc[t] = p;
  }
  __syncthreads();
  float ce[2], co[2];
  #pragma unroll
  for (int i = 0; i < 2; ++i) {
    int t = tid + i*256;
    ce[i] = -INFINITY; co[i] = 0.f;
    if (t < TSN) { co[i] = cov[b*TSN + t]; ce[i] = sc[t]*(1.f - co[i]); }
  }
  float m = fmaxf(ce[0], ce[1]);
  red[tid] = m; __syncthreads();
  for (int o = 128; o; o >>= 1) { if (tid < o) red[tid] = fmaxf(red[tid], red[tid+o]); __syncthreads(); }
  m = red[0]; __syncthreads();
  float ex[2]; float ssum = 0.f;
  #pragma unroll
  for (int i = 0; i < 2; ++i) {
    int t = tid + i*256; ex[i] = 0.f;
    if (t < TSN) { ex[i] = expf(ce[i] - m); ssum += ex[i]; }
  }
  red[tid] = ssum; __syncthreads();
  for (int o = 128; o; o >>= 1) { if (tid < o) red[tid] += red[tid+o]; __syncthreads(); }
  float inv = 1.f/red[0]; __syncthreads();
  float closs = 0.f;
  #pragma unroll
  for (int i = 0; i < 2; ++i) {
    int t = tid + i*256;
    if (t < TSN) {
      float a = ex[i]*inv;
      attnb[b*TSN + t] = a;
      cove[b*TSN + t]  = ce[i];
      cov[b*TSN + t]   = co[i] + a;
      closs += fminf(a, co[i]);
    }
  }
  red[tid] = closs; __syncthreads();
  for (int o = 128; o; o >>= 1) { if (tid < o) red[tid] += red[tid+o]; __syncthreads(); }
  if (tid == 0) atomicAdd(covacc, red[0]);
}

// ---------------- new_ctx (bf16) + cat upper half ----------------
__global__ __launch_bounds__(256) void k_dec_ctx2(
    const float* __restrict__ attnb, const float* __restrict__ memd,
    ushort* __restrict__ ctxbf, ushort* __restrict__ catbf)
{
  int b = blockIdx.x >> 2;
  int d = (blockIdx.x & 3)*256 + threadIdx.x;
  __shared__ float at[TSN];
  for (int i = threadIdx.x; i < TSN; i += 256) at[i] = attnb[b*TSN + i];
  __syncthreads();
  float s = 0.f;
  for (int t = 0; t < TSN; ++t) s += at[t]*memd[((long)b*TSN + t)*HD2 + d];
  ushort h = f2bf(s);
  ctxbf[b*HD2 + d] = h;
  catbf[(long)b*2048 + 1024 + d] = h;
}

// ---------------- scatter-max helpers ----------------
__device__ __forceinline__ unsigned enc_f(float f) {
  unsigned b = __float_as_uint(f);
  return (b & 0x80000000u) ? ~b : (b | 0x80000000u);
}
__device__ __forceinline__ float dec_f(unsigned e) {
  return (e & 0x80000000u) ? __uint_as_float(e ^ 0x80000000u) : __uint_as_float(~e);
}
__global__ __launch_bounds__(256) void k_scatter(
    const int* __restrict__ ids, const float* __restrict__ cove, unsigned* __restrict__ ubuf)
{
  int i = blockIdx.x*256 + threadIdx.x;
  if (i >= NB*TSN) return;
  int b = i / TSN;
  atomicMax(&ubuf[(long)b*NEXT + ids[i]], enc_f(cove[i]));
}
__global__ __launch_bounds__(256) void k_clear(
    const int* __restrict__ ids, unsigned* __restrict__ ubuf)
{
  int i = blockIdx.x*256 + threadIdx.x;
  if (i >= NB*TSN) return;
  int b = i / TSN;
  ubuf[(long)b*NEXT + ids[i]] = 0u;
}

// ---------------- hid = tanh(P + pb1) -> bf16 ----------------
__global__ __launch_bounds__(256) void k_comb_hid2(
    const float* __restrict__ P, const float* __restrict__ pb1, ushort* __restrict__ hidbf)
{
  int t = blockIdx.x*256 + threadIdx.x;
  int j = t & 1023;
  hidbf[t] = f2bf(tanhf(P[t] + pb1[j]));
}

// ---------------- logits via MFMA + copy-compose ----------------
__global__ __launch_bounds__(256) void k_logits_mfma(
    const ushort* __restrict__ hid, const ushort* __restrict__ pW2b,
    const float* __restrict__ pb2, const unsigned* __restrict__ ubuf,
    float* __restrict__ outp, int s)
{
  const int wave = threadIdx.x >> 6, lane = threadIdx.x & 63;
  const int lr = lane & 15, kg = lane >> 4;
  const int base = blockIdx.x*256 + wave*64;
  f32x4 acc[4] = {};
  const ushort* arow = hid + lr*1024 + kg*8;
  for (int k0 = 0; k0 < 1024; k0 += 32) {
    bf16x8 af = *(const bf16x8*)(arow + k0);
    #pragma unroll
    for (int nt = 0; nt < 4; ++nt) {
      bf16x8 bf = *(const bf16x8*)&pW2b[(long)(base + nt*16 + lr)*1024 + k0 + kg*8];
      acc[nt] = __builtin_amdgcn_mfma_f32_16x16x32_bf16(af, bf, acc[nt], 0, 0, 0);
    }
  }
  #pragma unroll
  for (int nt = 0; nt < 4; ++nt) {
    int v = base + nt*16 + lr;
    if (v >= NEXT) continue;
    #pragma unroll
    for (int r = 0; r < 4; ++r) {
      int b = kg*4 + r;
      unsigned u = ubuf[(long)b*NEXT + v];
      float o = u ? dec_f(u) : 0.f;
      float e = (v < NV) ? (acc[nt][r] + pb2[v]) : 0.f;
      float lg = e + o;
      if (lg == 0.f) lg = NEG_INF;
      outp[((long)b*NTT + s)*NEXT + v] = lg;
    }
  }
}

// ---------------- final coverage-loss scalar ----------------
__global__ void k_covout(const float* __restrict__ covacc, float* __restrict__ outp)
{
  outp[(long)NB*NTT*NEXT] = covacc[0] * (1.0f/(NB*NTT));
}

// ==================== host ====================
extern "C" void kernel_launch(void* const* d_in, const int* in_sizes, int n_in,
                              void* d_out, int out_size, void* d_ws, size_t ws_size,
                              hipStream_t stream) {
  (void)in_sizes; (void)n_in; (void)out_size; (void)ws_size;
  const float* enc_emb = (const float*)d_in[0];
  const float* ans_emb = (const float*)d_in[1];
  const float* dec_emb = (const float*)d_in[2];
  const float* eWi0 = (const float*)d_in[3];
  const float* eWh0 = (const float*)d_in[4];
  const float* ebi0 = (const float*)d_in[5];
  const float* ebh0 = (const float*)d_in[6];
  const float* eWi1 = (const float*)d_in[7];
  const float* eWh1 = (const float*)d_in[8];
  const float* ebi1 = (const float*)d_in[9];
  const float* ebh1 = (const float*)d_in[10];
  const float* trans_W = (const float*)d_in[11];
  const float* trans_b = (const float*)d_in[12];
  const float* upd_W = (const float*)d_in[13];
  const float* gate_W = (const float*)d_in[14];
  const float* dWi0 = (const float*)d_in[15];
  const float* dWh0 = (const float*)d_in[16];
  const float* dbi0 = (const float*)d_in[17];
  const float* dbh0 = (const float*)d_in[18];
  const float* dWi1 = (const float*)d_in[19];
  const float* dWh1 = (const float*)d_in[20];
  const float* dbi1 = (const float*)d_in[21];
  const float* dbh1 = (const float*)d_in[22];
  const float* dtrans_W = (const float*)d_in[23];
  const float* dtrans_b = (const float*)d_in[24];
  const float* pW1 = (const float*)d_in[25];
  const float* pb1 = (const float*)d_in[26];
  const float* pW2 = (const float*)d_in[27];
  const float* pb2 = (const float*)d_in[28];
  const int* input_s = (const int*)d_in[29];
  const int* ext_ids = (const int*)d_in[30];
  const int* input_q = (const int*)d_in[31];
  const int* input_a = (const int*)d_in[32];
  float* out = (float*)d_out;

  float* ws = (float*)d_ws;
  size_t off = 0;
  auto alloc = [&](size_t n) { float* p = ws + off; off += n; return p; };
  auto alloch = [&](size_t nh) { return (ushort*)alloc((nh + 1) / 2); };

  // --- small persistent ---
  float* hbuf  = alloc(2ull*2*NB*HENC);
  float* ghp   = alloc(4ull*2*NB*G3E);
  float* hfin0 = alloc(NB*HD2);
  float* hfin1 = alloc(NB*HD2);
  int*   bar   = (int*)alloc(16);
  float* covacc= alloc(4);
  float* cov   = alloc(NB*TSN);
  float* attnb = alloc(NB*TSN);
  float* cove  = alloc(NB*TSN);
  unsigned* ubuf = (unsigned*)alloc((size_t)NB*NEXT);
  float* dh0   = alloc(2ull*NB*HD2);
  float* dh1   = alloc(2ull*NB*HD2);
  ushort* h0b  = alloch(2ull*NB*HD2);
  ushort* h1b  = alloch(2ull*NB*HD2);
  ushort* ctxbf= alloch(2ull*NB*HD2);
  ushort* catbf= alloch((size_t)NB*2048);
  ushort* hidbf= alloch((size_t)NB*HD2);
  float* p_gx  = alloc((size_t)NB*G3D);
  float* p_gh  = alloc((size_t)NB*G3D);
  float* p_gx1 = alloc((size_t)NB*G3D);
  float* p_gh1 = alloc((size_t)NB*G3D);
  float* p_hid = alloc((size_t)NB*HD2);

  // --- bf16 weights (persistent) ---
  ushort* eWi0c   = alloch(2ull*G3E*384);
  ushort* eWi1c   = alloch(2ull*G3E*1024);
  ushort* WhT0b   = alloch(2ull*HENC*G3E);
  ushort* WhT1b   = alloch(2ull*HENC*G3E);
  ushort* transWb = alloch(1024ull*1024);
  ushort* updWb   = alloch(1024ull*2048);
  ushort* gateWb  = alloch(1024ull*2048);
  ushort* dtransWb= alloch(1024ull*1024);
  ushort* dWi0e   = alloch(3072ull*320);
  ushort* dWi0c   = alloch(3072ull*1024);
  ushort* dWh0b   = alloch(3072ull*1024);
  ushort* dWi1b   = alloch(3072ull*1024);
  ushort* dWh1b   = alloch(3072ull*1024);
  ushort* pW1b    = alloch(1024ull*2048);

  // --- alias region: GX + X0c + Y0bf + ft  (later reused as pW2b) ---
  size_t regionStart = off;
  float*  GX   = alloc(2ull*6400*G3E);        // 19.66M f
  ushort* X0c  = alloch(6400ull*384);         // 1.23M f
  ushort* Y0bf = alloch(6400ull*1024);        // 3.28M f
  float*  ft   = alloc(6400ull*HD2);          // 6.55M f
  ushort* pW2b = (ushort*)(ws + regionStart); // 25.69M f needed; region = 30.7M f

  // --- remaining big buffers ---
  float* outp    = alloc(6400ull*HD2);
  ushort* outpbf = alloch(6400ull*HD2);
  float* mems    = alloc(6400ull*HD2);
  ushort* memsbf = alloch(6400ull*HD2);
  size_t eregion = off;
  float* energ   = alloc((size_t)NB*TSN*TSN);   // 2.56M
  float* ctx     = alloc(6400ull*HD2);          // 6.55M
  float* memd    = ws + eregion;                // aliases energ+ctx (6.55M <= 9.11M)
  ushort* ctx_bf = alloch(6400ull*HD2);
  float* gt      = alloc(6400ull*HD2);
  ushort* encbf  = alloch(6400ull*HD2);
  ushort* embqb  = alloch(512ull*320);
  float* embGX   = alloc(512ull*G3D);

  // ---------------- one-time weight casts ----------------
  k_embed_bf<<<9600, 256, 0, stream>>>(enc_emb, ans_emb, input_s, input_a, X0c);
  k_transpose_bf<<<dim3(48,16), 256, 0, stream>>>(eWh0,            WhT0b,            G3E, HENC, HENC);
  k_transpose_bf<<<dim3(48,16), 256, 0, stream>>>(eWh0 + (long)G3E*HENC, WhT0b + (long)HENC*G3E, G3E, HENC, HENC);
  k_transpose_bf<<<dim3(48,16), 256, 0, stream>>>(eWh1,            WhT1b,            G3E, HENC, HENC);
  k_transpose_bf<<<dim3(48,16), 256, 0, stream>>>(eWh1 + (long)G3E*HENC, WhT1b + (long)HENC*G3E, G3E, HENC, HENC);
  k_castw<<<4608, 256, 0, stream>>>(eWi0, eWi0c, 3072, 3072ull*384, 332, 384, 332, 0);
  k_castw<<<12288, 256, 0, stream>>>(eWi1, eWi1c, 3072, 3072ull*1024, 1024, 1024, 1024, 0);
  k_castw<<<4096, 256, 0, stream>>>(trans_W, transWb, 1024, 1024ull*1024, 1024, 1024, 1024, 0);
  k_castw<<<8192, 256, 0, stream>>>(upd_W,  updWb,  1024, 1024ull*2048, 2048, 2048, 2048, 0);
  k_castw<<<8192, 256, 0, stream>>>(gate_W, gateWb, 1024, 1024ull*2048, 2048, 2048, 2048, 0);
  k_castw<<<4096, 256, 0, stream>>>(dtrans_W, dtransWb, 1024, 1024ull*1024, 1024, 1024, 1024, 0);
  k_castw<<<3840, 256, 0, stream>>>(dWi0, dWi0e, 3072, 3072ull*320, 300, 320, 1324, 0);
  k_castw<<<12288, 256, 0, stream>>>(dWi0, dWi0c, 3072, 3072ull*1024, 1024, 1024, 1324, 300);
  k_castw<<<12288, 256, 0, stream>>>(dWh0, dWh0b, 3072, 3072ull*1024, 1024, 1024, 1024, 0);
  k_castw<<<12288, 256, 0, stream>>>(dWi1, dWi1b, 3072, 3072ull*1024, 1024, 1024, 1024, 0);
  k_castw<<<12288, 256, 0, stream>>>(dWh1, dWh1b, 3072, 3072ull*1024, 1024, 1024, 1024, 0);
  k_castw<<<8192, 256, 0, stream>>>(pW1, pW1b, 1024, 1024ull*2048, 2048, 2048, 2048, 0);

  // ---------------- encoder layer 0 ----------------
  k_mfma_nt<<<dim3(100,24,2), 256, 0, stream>>>(X0c, eWi0c, ebi0, GX, nullptr,
      6400, G3E, 384, 384, 384, G3E, 0, (long)G3E*384, 6400ull*G3E, G3E, 0, 0);
  hipMemsetAsync(hbuf, 0, 2ull*2*NB*HENC*4, stream);
  hipMemsetAsync(bar, 0, 16, stream);
  k_scan<<<64, 256, 0, stream>>>(GX, GX + 6400ull*G3E, WhT0b, ebh0,
      nullptr, Y0bf, 0, hfin0, hbuf, ghp, bar);
  // ---------------- encoder layer 1 ----------------
  k_mfma_nt<<<dim3(100,24,2), 256, 0, stream>>>(Y0bf, eWi1c, ebi1, GX, nullptr,
      6400, G3E, 1024, 1024, 1024, G3E, 0, (long)G3E*1024, 6400ull*G3E, G3E, 0, 0);
  hipMemsetAsync(hbuf, 0, 2ull*2*NB*HENC*4, stream);
  hipMemsetAsync(bar, 0, 16, stream);
  k_scan<<<64, 256, 0, stream>>>(GX, GX + 6400ull*G3E, WhT1b, ebh1,
      outp, outpbf, 1, hfin1, hbuf, ghp, bar);

  // ---------------- self/answer attention ----------------
  k_mfma_nt<<<dim3(100,16,1), 256, 0, stream>>>(outpbf, transWb, trans_b, mems, memsbf,
      6400, HD2, 1024, 1024, 1024, HD2, 0, 0, 0, 0, 0, 0);
  k_mfma_nt<<<dim3(7,7,16), 256, 0, stream>>>(outpbf, memsbf, nullptr, energ, nullptr,
      TSN, TSN, 1024, 1024, 1024, TSN, (long)TSN*1024, (long)TSN*1024, (long)TSN*TSN, 0, 0, 0);
  k_softmax<<<NB*TSN, 256, 0, stream>>>(energ, TSN);
  k_gemm_nn<<<dim3(7,16,16), 256, 0, stream>>>(energ, outp, ctx, TSN, HD2, TSN, TSN, HD2, HD2,
      (long)TSN*TSN, (long)TSN*HD2, (long)TSN*HD2);
  k_cast<<<25600, 256, 0, stream>>>(ctx, ctx_bf, 6553600L);
  k_mfma_nt<<<dim3(100,16,1), 256, 0, stream>>>(outpbf, updWb,        nullptr, ft, nullptr,
      6400, HD2, 1024, 1024, 2048, HD2, 0, 0, 0, 0, 0, 0);
  k_mfma_nt<<<dim3(100,16,1), 256, 0, stream>>>(ctx_bf, updWb + 1024, nullptr, ft, nullptr,
      6400, HD2, 1024, 1024, 2048, HD2, 0, 0, 0, 0, 1, 1);
  k_mfma_nt<<<dim3(100,16,1), 256, 0, stream>>>(outpbf, gateWb,       nullptr, gt, nullptr,
      6400, HD2, 1024, 1024, 2048, HD2, 0, 0, 0, 0, 0, 0);
  k_mfma_nt<<<dim3(100,16,1), 256, 0, stream>>>(ctx_bf, gateWb + 1024, nullptr, gt, nullptr,
      6400, HD2, 1024, 1024, 2048, HD2, 0, 0, 0, 0, 1, 2);
  k_selfcomb<<<25600, 256, 0, stream>>>(ft, gt, outp, 6553600L);
  k_ansatt<<<64, 256, 0, stream>>>(mems, ft, input_a, gt);   // enc_out -> gt
  // ft (and GX/X0c/Y0bf) now dead: cast pW2 into the alias region
  k_castw<<<200704, 256, 0, stream>>>(pW2, pW2b, NV, (long)NVP*1024, 1024, 1024, 1024, 0);
  k_cast<<<25600, 256, 0, stream>>>(gt, encbf, 6553600L);
  k_mfma_nt<<<dim3(100,16,1), 256, 0, stream>>>(encbf, dtransWb, dtrans_b, memd, nullptr,
      6400, HD2, 1024, 1024, 1024, HD2, 0, 0, 0, 0, 0, 0);

  // ---------------- decoder precompute ----------------
  k_embq_bf<<<640, 256, 0, stream>>>(dec_emb, input_q, embqb);
  k_mfma_nt<<<dim3(8,48,1), 256, 0, stream>>>(embqb, dWi0e, dbi0, embGX, nullptr,
      NTT*NB, G3D, 320, 320, 320, G3D, 0, 0, 0, 0, 0, 0);

  hipMemsetAsync(cov, 0, (size_t)NB*TSN*4, stream);
  hipMemsetAsync(covacc, 0, 4, stream);
  hipMemsetAsync(ubuf, 0, (size_t)NB*NEXT*4, stream);
  hipMemsetAsync(ctxbf, 0, 2ull*NB*HD2*2, stream);
  hipMemcpyAsync(dh0, hfin0, (size_t)NB*HD2*4, hipMemcpyDeviceToDevice, stream);
  hipMemcpyAsync(dh1, hfin1, (size_t)NB*HD2*4, hipMemcpyDeviceToDevice, stream);
  k_cast<<<64, 256, 0, stream>>>(hfin0, h0b, 16384);
  k_cast<<<64, 256, 0, stream>>>(hfin1, h1b, 16384);

  // ---------------- decoder steps ----------------
  for (int s = 0; s < NTT; ++s) {
    int cur = s & 1, nxt = cur ^ 1;
    float* h0c = dh0 + (size_t)cur*NB*HD2;  float* h0n = dh0 + (size_t)nxt*NB*HD2;
    float* h1c = dh1 + (size_t)cur*NB*HD2;  float* h1n = dh1 + (size_t)nxt*NB*HD2;
    ushort* h0bc = h0b + (size_t)cur*NB*HD2; ushort* h0bn = h0b + (size_t)nxt*NB*HD2;
    ushort* h1bc = h1b + (size_t)cur*NB*HD2; ushort* h1bn = h1b + (size_t)nxt*NB*HD2;
    ushort* ctxc = ctxbf + (size_t)cur*NB*HD2; ushort* ctxn = ctxbf + (size_t)nxt*NB*HD2;

    k_skinny<<<dim3(48,2), 256, 0, stream>>>(ctxc, dWi0c, p_gx, h0bc, dWh0b, p_gh, G3D, 1024);
    k_comb_gru2<<<64, 256, 0, stream>>>(p_gx, embGX + (size_t)s*NB*G3D, nullptr, p_gh, dbh0,
                                        h0c, h0n, h0bn, nullptr);
    k_skinny<<<dim3(48,2), 256, 0, stream>>>(h0bn, dWi1b, p_gx1, h1bc, dWh1b, p_gh1, G3D, 1024);
    k_comb_gru2<<<64, 256, 0, stream>>>(p_gx1, nullptr, dbi1, p_gh1, dbh1,
                                        h1c, h1n, h1bn, catbf);
    k_dec_attn<<<NB, 256, 0, stream>>>(h1n, memd, cov, attnb, cove, covacc);
    k_dec_ctx2<<<64, 256, 0, stream>>>(attnb, memd, ctxn, catbf);
    k_scatter<<<25, 256, 0, stream>>>(ext_ids, cove, ubuf);
    k_skinny<<<dim3(16,1), 256, 0, stream>>>(catbf, pW1b, p_hid, catbf, pW1b, p_hid, HD2, 2048);
    k_comb_hid2<<<64, 256, 0, stream>>>(p_hid, pb1, hidbf);
    k_logits_mfma<<<196, 256, 0, stream>>>(hidbf, pW2b, pb2, ubuf, out, s);
    k_clear<<<25, 256, 0, stream>>>(ext_ids, ubuf);
  }
  k_covout<<<1, 1, 0, stream>>>(covacc, out);
}

// Round 3
// 15553.175 us; speedup vs baseline: 2.5604x; 1.5319x over previous
//
#include <hip/hip_runtime.h>
#include <stdint.h>

#define TSN 400
#define NB 16
#define HENC 512
#define HD2 1024
#define G3E 1536
#define G3D 3072
#define EMBD 300
#define AEMB 32
#define NV 50000
#define NEXT 50100
#define NVP 50176
#define NTT 32
#define NEG_INF (-1.0e12f)

typedef __attribute__((ext_vector_type(8))) short bf16x8;
typedef __attribute__((ext_vector_type(4))) float f32x4;

__device__ __forceinline__ ushort f2bf(float f) {
  unsigned u = __float_as_uint(f);
  unsigned r = (u + 0x7fffu + ((u >> 16) & 1u)) >> 16;
  return (ushort)r;
}
__device__ __forceinline__ float bf2f(ushort h) {
  return __uint_as_float((unsigned)h << 16);
}

// ---------------- sense-style grid barrier: counter + broadcast flag ----------------
__device__ __forceinline__ void gridbar2(int* cnt, int* flag, int nblocks, int epoch) {
  __syncthreads();
  if (threadIdx.x == 0) {
    __threadfence();
    int old = __hip_atomic_fetch_add(cnt, 1, __ATOMIC_ACQ_REL, __HIP_MEMORY_SCOPE_AGENT);
    if (old == nblocks*epoch - 1) {
      __hip_atomic_store(flag, epoch, __ATOMIC_RELEASE, __HIP_MEMORY_SCOPE_AGENT);
    } else {
      while (__hip_atomic_load(flag, __ATOMIC_ACQUIRE, __HIP_MEMORY_SCOPE_AGENT) < epoch)
        __builtin_amdgcn_s_sleep(1);
    }
  }
  __syncthreads();
}

// ---------------- embeddings -> bf16, padded K=384 ----------------
__global__ __launch_bounds__(256) void k_embed_bf(
    const float* __restrict__ enc_emb, const float* __restrict__ ans_emb,
    const int* __restrict__ input_s, const int* __restrict__ input_a,
    ushort* __restrict__ X0)
{
  long i = (long)blockIdx.x*256 + threadIdx.x;
  if (i >= (long)TSN*NB*384) return;
  int c = (int)(i % 384);
  long r = i / 384;
  int b = (int)(r % NB);
  int t = (int)(r / NB);
  float v = 0.f;
  if (c < EMBD) v = enc_emb[(long)input_s[b*TSN + t]*EMBD + c];
  else if (c < 332) v = ans_emb[(long)input_a[b*TSN + t]*AEMB + (c - EMBD)];
  X0[i] = f2bf(v);
}

// ---------------- decoder emb -> bf16, padded K=320 ----------------
__global__ __launch_bounds__(256) void k_embq_bf(
    const float* __restrict__ dec_emb, const int* __restrict__ input_q,
    ushort* __restrict__ EQ)
{
  long i = (long)blockIdx.x*256 + threadIdx.x;
  if (i >= (long)NTT*NB*320) return;
  int c = (int)(i % 320);
  long r = i / 320;
  int b = (int)(r % NB);
  int s = (int)(r / NB);
  EQ[i] = (c < EMBD) ? f2bf(dec_emb[(long)input_q[b*33 + s]*EMBD + c]) : (ushort)0;
}

// ---------------- weight cast with pad ----------------
__global__ __launch_bounds__(256) void k_castw(
    const float* __restrict__ src, ushort* __restrict__ dst,
    int Nsrc, long total, int Ksrc, int Kdst, int ldsrc, int coloff)
{
  long i = (long)blockIdx.x*256 + threadIdx.x;
  if (i >= total) return;
  int k = (int)(i % Kdst);
  long n = i / Kdst;
  float v = (n < Nsrc && k < Ksrc) ? src[n*ldsrc + coloff + k] : 0.f;
  dst[i] = f2bf(v);
}

// ---------------- plain cast fp32 -> bf16 ----------------
__global__ __launch_bounds__(256) void k_cast(
    const float* __restrict__ s, ushort* __restrict__ d, long n)
{
  long i = (long)blockIdx.x*256 + threadIdx.x;
  if (i >= n) return;
  d[i] = f2bf(s[i]);
}

// ---------------- bf16 batched transpose with K-pad: out[b][c][r(448)] ----------------
__global__ __launch_bounds__(256) void k_transpose_hh(
    const ushort* __restrict__ in, ushort* __restrict__ out)
{
  __shared__ ushort tb[32][33];
  int b = blockIdx.z;
  int r0 = blockIdx.x*32, c0 = blockIdx.y*32;
  int tx = threadIdx.x & 31, ty = threadIdx.x >> 5;
  #pragma unroll
  for (int i = 0; i < 32; i += 8) {
    int r = r0 + ty + i, c = c0 + tx;
    tb[ty+i][tx] = (r < TSN) ? in[((long)b*TSN + r)*1024 + c] : (ushort)0;
  }
  __syncthreads();
  #pragma unroll
  for (int i = 0; i < 32; i += 8) {
    int c = c0 + ty + i, r = r0 + tx;
    out[((long)b*1024 + c)*448 + r] = tb[tx][ty+i];
  }
}

// ---------------- MFMA GEMM (proven round-2 kernel) ----------------
__global__ __launch_bounds__(256) void k_mfma_nt(
    const ushort* __restrict__ Ab, const ushort* __restrict__ Wb,
    const float* __restrict__ bias, float* __restrict__ Cb, ushort* __restrict__ C2b,
    int M, int N, int K, int lda, int ldw, int ldc,
    long sA, long sW, long sC, long sBias, int accum, int act)
{
  __shared__ ushort As[64][72];
  __shared__ ushort Ws[64][72];
  const ushort* A = Ab + (long)blockIdx.z * sA;
  const ushort* W = Wb + (long)blockIdx.z * sW;
  float* C = Cb + (long)blockIdx.z * sC;
  const float* bi = bias ? bias + (long)blockIdx.z * sBias : nullptr;
  const int m0 = blockIdx.x*64, n0 = blockIdx.y*64;
  const int tid = threadIdx.x;
  const int wave = tid >> 6, lane = tid & 63;
  const int wm = wave >> 1, wn = wave & 1;
  const int lr = lane & 15, kg = lane >> 4;
  f32x4 acc[2][2] = {};
  for (int k0 = 0; k0 < K; k0 += 64) {
    __syncthreads();
    #pragma unroll
    for (int it = 0; it < 2; ++it) {
      int sidx = tid + it*256;
      int r = sidx >> 3, c = (sidx & 7)*8;
      bf16x8 av = {};
      bf16x8 wv = {};
      if (m0 + r < M) av = *(const bf16x8*)&A[(long)(m0+r)*lda + k0 + c];
      if (n0 + r < N) wv = *(const bf16x8*)&W[(long)(n0+r)*ldw + k0 + c];
      *(bf16x8*)&As[r][c] = av;
      *(bf16x8*)&Ws[r][c] = wv;
    }
    __syncthreads();
    #pragma unroll
    for (int kk = 0; kk < 2; ++kk) {
      bf16x8 af[2], bf[2];
      #pragma unroll
      for (int mt = 0; mt < 2; ++mt)
        af[mt] = *(const bf16x8*)&As[wm*32 + mt*16 + lr][kk*32 + kg*8];
      #pragma unroll
      for (int nt = 0; nt < 2; ++nt)
        bf[nt] = *(const bf16x8*)&Ws[wn*32 + nt*16 + lr][kk*32 + kg*8];
      #pragma unroll
      for (int mt = 0; mt < 2; ++mt)
        #pragma unroll
        for (int nt = 0; nt < 2; ++nt)
          acc[mt][nt] = __builtin_amdgcn_mfma_f32_16x16x32_bf16(af[mt], bf[nt], acc[mt][nt], 0, 0, 0);
    }
  }
  #pragma unroll
  for (int mt = 0; mt < 2; ++mt) {
    #pragma unroll
    for (int r = 0; r < 4; ++r) {
      int m = m0 + wm*32 + mt*16 + kg*4 + r;
      if (m >= M) continue;
      #pragma unroll
      for (int nt = 0; nt < 2; ++nt) {
        int n = n0 + wn*32 + nt*16 + lr;
        if (n >= N) continue;
        float v = acc[mt][nt][r];
        if (accum) v += C[(long)m*ldc + n];
        if (bi)    v += bi[n];
        if (act == 1) v = tanhf(v);
        else if (act == 2) v = 1.f/(1.f + expf(-v));
        C[(long)m*ldc + n] = v;
        if (C2b) C2b[(long)blockIdx.z*sC + (long)m*ldc + n] = f2bf(v);
      }
    }
  }
}

// ---------------- persistent MFMA bidirectional GRU scan: 16 blocks, 1 barrier/step ----------------
__global__ __launch_bounds__(256) void k_scan_mfma(
    const float* __restrict__ GXf, const float* __restrict__ GXb,
    const ushort* __restrict__ Whb,   // [2][1536][512] bf16
    const float* __restrict__ bh,     // [2][1536]
    float* __restrict__ Yf, ushort* __restrict__ Ybf, int bmajor,
    float* __restrict__ hfin,
    ushort* __restrict__ hpp,         // [2 ping][2 dir][16][512] bf16
    int* cnt, int* flag)
{
  const int wg = blockIdx.x*4 + (threadIdx.x >> 6);
  const int lane = threadIdx.x & 63;
  const int lr = lane & 15, kg = lane >> 4;
  const int dir = wg >> 5, jt = wg & 31;
  const int j = jt*16 + lr;
  const ushort* Wp0 = Whb + ((long)(dir*G3E + j)        << 9) + kg*8;
  const ushort* Wp1 = Whb + ((long)(dir*G3E + 512 + j)  << 9) + kg*8;
  const ushort* Wp2 = Whb + ((long)(dir*G3E + 1024 + j) << 9) + kg*8;
  const float bh0 = bh[dir*G3E + j];
  const float bh1 = bh[dir*G3E + 512 + j];
  const float bh2 = bh[dir*G3E + 1024 + j];
  const float* GX = dir ? GXb : GXf;
  float hreg[4] = {0.f, 0.f, 0.f, 0.f};
  for (int s = 0; s < TSN; ++s) {
    const int cur = s & 1;
    const int t = dir ? (TSN - 1 - s) : s;
    const float* gxp = GX + (long)t*16*G3E;
    float gx0[4], gx1v[4], gx2v[4];
    #pragma unroll
    for (int r = 0; r < 4; ++r) {
      const float* g = gxp + (long)(kg*4 + r)*G3E + j;
      gx0[r] = g[0]; gx1v[r] = g[512]; gx2v[r] = g[1024];
    }
    const ushort* hA = hpp + (((cur<<1) + dir)*16 + lr)*512 + kg*8;
    f32x4 a0 = {}, a1 = {}, a2 = {};
    #pragma unroll 8
    for (int k0 = 0; k0 < 512; k0 += 32) {
      bf16x8 af = *(const bf16x8*)(hA + k0);
      a0 = __builtin_amdgcn_mfma_f32_16x16x32_bf16(af, *(const bf16x8*)(Wp0 + k0), a0, 0, 0, 0);
      a1 = __builtin_amdgcn_mfma_f32_16x16x32_bf16(af, *(const bf16x8*)(Wp1 + k0), a1, 0, 0, 0);
      a2 = __builtin_amdgcn_mfma_f32_16x16x32_bf16(af, *(const bf16x8*)(Wp2 + k0), a2, 0, 0, 0);
    }
    ushort* hO = hpp + (((cur^1)<<1) + dir)*16*512;
    #pragma unroll
    for (int r = 0; r < 4; ++r) {
      int b = kg*4 + r;
      float rr = 1.f/(1.f + expf(-(gx0[r]  + a0[r] + bh0)));
      float zz = 1.f/(1.f + expf(-(gx1v[r] + a1[r] + bh1)));
      float nn = tanhf(gx2v[r] + rr*(a2[r] + bh2));
      float hn = (1.f - zz)*nn + zz*hreg[r];
      hreg[r] = hn;
      hO[b*512 + j] = f2bf(hn);
      long yi = bmajor ? ((long)b*TSN + t)*1024 + dir*512 + j
                       : ((long)t*16 + b)*1024 + dir*512 + j;
      if (Yf) Yf[yi] = hn;
      Ybf[yi] = f2bf(hn);
      if (s == TSN - 1) hfin[b*1024 + dir*512 + j] = hn;
    }
    gridbar2(cnt, flag, 16, s + 1);
  }
}

// ---------------- row softmax f32 -> bf16 (pad to 448) ----------------
__global__ __launch_bounds__(256) void k_softmax_bf(
    const float* __restrict__ E, ushort* __restrict__ S)
{
  long row = blockIdx.x;
  const float* x = E + row*TSN;
  ushort* o = S + row*448;
  int tid = threadIdx.x;
  float v0 = (tid < TSN) ? x[tid] : -INFINITY;
  float v1 = (tid + 256 < TSN) ? x[tid + 256] : -INFINITY;
  __shared__ float red[256];
  red[tid] = fmaxf(v0, v1); __syncthreads();
  for (int oo = 128; oo; oo >>= 1) { if (tid < oo) red[tid] = fmaxf(red[tid], red[tid+oo]); __syncthreads(); }
  float m = red[0]; __syncthreads();
  float e0 = (tid < TSN) ? expf(v0 - m) : 0.f;
  float e1 = (tid + 256 < TSN) ? expf(v1 - m) : 0.f;
  red[tid] = e0 + e1; __syncthreads();
  for (int oo = 128; oo; oo >>= 1) { if (tid < oo) red[tid] += red[tid+oo]; __syncthreads(); }
  float inv = 1.f/red[0];
  if (tid < 192) o[tid + 256] = (tid + 256 < TSN) ? f2bf(e1*inv) : (ushort)0;
  o[tid] = f2bf(e0*inv);
}

// ---------------- fused selfcomb + answer attention -> encbf ----------------
__global__ __launch_bounds__(256) void k_ansatt2(
    const ushort* __restrict__ memsb, const float* __restrict__ ft,
    const float* __restrict__ gt, const ushort* __restrict__ outpb,
    const int* __restrict__ input_a, ushort* __restrict__ encb)
{
  int b = blockIdx.x >> 2;
  int d = (blockIdx.x & 3)*256 + threadIdx.x;
  __shared__ int ia[TSN];
  for (int i = threadIdx.x; i < TSN; i += 256) ia[i] = input_a[b*TSN + i];
  __syncthreads();
  float m = -INFINITY;
  for (int t = 0; t < TSN; ++t) {
    float v = bf2f(memsb[((long)b*TSN + t)*1024 + d]);
    float e = ia[t] ? v*v : v;
    m = fmaxf(m, e);
  }
  float ssum = 0.f;
  for (int t = 0; t < TSN; ++t) {
    float v = bf2f(memsb[((long)b*TSN + t)*1024 + d]);
    float e = ia[t] ? v*v : v;
    ssum += expf(e - m);
  }
  float inv = 1.f/ssum;
  for (int t = 0; t < TSN; ++t) {
    long idx = ((long)b*TSN + t)*1024 + d;
    float v = bf2f(memsb[idx]);
    float e = ia[t] ? v*v : v;
    float gg = gt[idx];
    float selfo = gg*ft[idx] + (1.f - gg)*bf2f(outpb[idx]);
    encb[idx] = f2bf(selfo + expf(e - m)*inv*v);
  }
}

// ---------------- decoder GRU layer: 16 blocks, MFMA, fused combine ----------------
__global__ __launch_bounds__(256) void k_gru_dec(
    const ushort* __restrict__ A1, const ushort* __restrict__ W1,
    const ushort* __restrict__ A2, const ushort* __restrict__ W2,
    const float* __restrict__ gxadd, const float* __restrict__ bi,
    const float* __restrict__ bh,
    const float* __restrict__ hprev, float* __restrict__ hout,
    ushort* __restrict__ houtb, ushort* __restrict__ catb)
{
  const int wg = blockIdx.x*4 + (threadIdx.x >> 6);
  const int lane = threadIdx.x & 63;
  const int lr = lane & 15, kg = lane >> 4;
  const int j = wg*16 + lr;
  const ushort* w1p0 = W1 + ((long)(j)        << 10) + kg*8;
  const ushort* w1p1 = W1 + ((long)(1024 + j) << 10) + kg*8;
  const ushort* w1p2 = W1 + ((long)(2048 + j) << 10) + kg*8;
  const ushort* w2p0 = W2 + ((long)(j)        << 10) + kg*8;
  const ushort* w2p1 = W2 + ((long)(1024 + j) << 10) + kg*8;
  const ushort* w2p2 = W2 + ((long)(2048 + j) << 10) + kg*8;
  const ushort* a1p = A1 + lr*1024 + kg*8;
  const ushort* a2p = A2 + lr*1024 + kg*8;
  f32x4 x0 = {}, x1 = {}, x2 = {}, h0 = {}, h1 = {}, h2 = {};
  #pragma unroll 4
  for (int k0 = 0; k0 < 1024; k0 += 32) {
    bf16x8 a1v = *(const bf16x8*)(a1p + k0);
    bf16x8 a2v = *(const bf16x8*)(a2p + k0);
    x0 = __builtin_amdgcn_mfma_f32_16x16x32_bf16(a1v, *(const bf16x8*)(w1p0 + k0), x0, 0, 0, 0);
    x1 = __builtin_amdgcn_mfma_f32_16x16x32_bf16(a1v, *(const bf16x8*)(w1p1 + k0), x1, 0, 0, 0);
    x2 = __builtin_amdgcn_mfma_f32_16x16x32_bf16(a1v, *(const bf16x8*)(w1p2 + k0), x2, 0, 0, 0);
    h0 = __builtin_amdgcn_mfma_f32_16x16x32_bf16(a2v, *(const bf16x8*)(w2p0 + k0), h0, 0, 0, 0);
    h1 = __builtin_amdgcn_mfma_f32_16x16x32_bf16(a2v, *(const bf16x8*)(w2p1 + k0), h1, 0, 0, 0);
    h2 = __builtin_amdgcn_mfma_f32_16x16x32_bf16(a2v, *(const bf16x8*)(w2p2 + k0), h2, 0, 0, 0);
  }
  float bi0 = bi ? bi[j] : 0.f, bi1 = bi ? bi[1024 + j] : 0.f, bi2 = bi ? bi[2048 + j] : 0.f;
  float bh0 = bh[j], bh1 = bh[1024 + j], bh2 = bh[2048 + j];
  #pragma unroll
  for (int r = 0; r < 4; ++r) {
    int b = kg*4 + r;
    float gxa0 = gxadd ? gxadd[(long)b*G3D + j]        : 0.f;
    float gxa1 = gxadd ? gxadd[(long)b*G3D + 1024 + j] : 0.f;
    float gxa2 = gxadd ? gxadd[(long)b*G3D + 2048 + j] : 0.f;
    float gx0 = x0[r] + gxa0 + bi0;
    float gx1 = x1[r] + gxa1 + bi1;
    float gx2 = x2[r] + gxa2 + bi2;
    float gh0 = h0[r] + bh0, gh1 = h1[r] + bh1, gh2 = h2[r] + bh2;
    float rr = 1.f/(1.f + expf(-(gx0 + gh0)));
    float zz = 1.f/(1.f + expf(-(gx1 + gh1)));
    float nn = tanhf(gx2 + rr*gh2);
    float hp = hprev[b*1024 + j];
    float hn = (1.f - zz)*nn + zz*hp;
    hout[b*1024 + j] = hn;
    houtb[b*1024 + j] = f2bf(hn);
    if (catb) catb[(long)b*2048 + j] = f2bf(hn);
  }
}

// ---------------- fused decoder attention: energy + cov-softmax + scatter + ctx ----------------
__global__ __launch_bounds__(1024) void k_dec_attn2(
    const ushort* __restrict__ h1b, const ushort* __restrict__ memdb,
    const int* __restrict__ ids,
    float* __restrict__ cov, unsigned* __restrict__ ubuf, float* __restrict__ covacc,
    ushort* __restrict__ ctxn, ushort* __restrict__ catb)
{
  const int b = blockIdx.x, tid = threadIdx.x;
  const int wv = tid >> 6, ln = tid & 63;
  __shared__ float sc[TSN];
  __shared__ float at[TSN];
  __shared__ float red[1024];
  float hreg[16];
  {
    bf16x8 hv0 = *(const bf16x8*)&h1b[b*1024 + ln*16];
    bf16x8 hv1 = *(const bf16x8*)&h1b[b*1024 + ln*16 + 8];
    #pragma unroll
    for (int e = 0; e < 8; ++e) { hreg[e] = bf2f((ushort)hv0[e]); hreg[8+e] = bf2f((ushort)hv1[e]); }
  }
  for (int t = wv; t < TSN; t += 16) {
    const ushort* row = memdb + ((long)b*TSN + t)*1024 + ln*16;
    bf16x8 r0 = *(const bf16x8*)row;
    bf16x8 r1 = *(const bf16x8*)(row + 8);
    float p = 0.f;
    #pragma unroll
    for (int e = 0; e < 8; ++e) p += hreg[e]*bf2f((ushort)r0[e]) + hreg[8+e]*bf2f((ushort)r1[e]);
    #pragma unroll
    for (int off = 32; off; off >>= 1) p += __shfl_xor(p, off);
    if (ln == 0) sc[t] = p;
  }
  __syncthreads();
  float ce = -INFINITY, co = 0.f;
  if (tid < TSN) { co = cov[b*TSN + tid]; ce = sc[tid]*(1.f - co); }
  red[tid] = ce; __syncthreads();
  for (int o = 512; o; o >>= 1) { if (tid < o) red[tid] = fmaxf(red[tid], red[tid+o]); __syncthreads(); }
  float m = red[0]; __syncthreads();
  float ex = (tid < TSN) ? expf(ce - m) : 0.f;
  red[tid] = ex; __syncthreads();
  for (int o = 512; o; o >>= 1) { if (tid < o) red[tid] += red[tid+o]; __syncthreads(); }
  float inv = 1.f/red[0]; __syncthreads();
  float closs = 0.f;
  if (tid < TSN) {
    float a = ex*inv;
    at[tid] = a;
    cov[b*TSN + tid] = co + a;
    unsigned eb = __float_as_uint(ce);
    unsigned enc = (eb & 0x80000000u) ? ~eb : (eb | 0x80000000u);
    atomicMax(&ubuf[(long)b*NEXT + ids[b*TSN + tid]], enc);
    closs = fminf(a, co);
  }
  red[tid] = closs; __syncthreads();
  for (int o = 512; o; o >>= 1) { if (tid < o) red[tid] += red[tid+o]; __syncthreads(); }
  if (tid == 0) atomicAdd(covacc, red[0]);
  __syncthreads();
  // ctx
  float s = 0.f;
  const ushort* col = memdb + (long)b*TSN*1024 + tid;
  #pragma unroll 8
  for (int t = 0; t < TSN; ++t) s += at[t]*bf2f(col[(long)t*1024]);
  ushort hv = f2bf(s);
  ctxn[b*1024 + tid] = hv;
  catb[(long)b*2048 + 1024 + tid] = hv;
}

// ---------------- hid = tanh(cat @ pW1^T + pb1) -> bf16, MFMA ----------------
__global__ __launch_bounds__(256) void k_hid(
    const ushort* __restrict__ catb, const ushort* __restrict__ W,
    const float* __restrict__ pb1, ushort* __restrict__ hidb)
{
  const int wg = blockIdx.x*4 + (threadIdx.x >> 6);
  const int lane = threadIdx.x & 63;
  const int lr = lane & 15, kg = lane >> 4;
  const int n = wg*16 + lr;
  f32x4 acc = {};
  const ushort* ap = catb + lr*2048 + kg*8;
  const ushort* wp = W + ((long)n << 11) + kg*8;
  #pragma unroll 8
  for (int k0 = 0; k0 < 2048; k0 += 32)
    acc = __builtin_amdgcn_mfma_f32_16x16x32_bf16(*(const bf16x8*)(ap + k0), *(const bf16x8*)(wp + k0), acc, 0, 0, 0);
  float bv = pb1[n];
  #pragma unroll
  for (int r = 0; r < 4; ++r) {
    int b = kg*4 + r;
    hidb[b*1024 + n] = f2bf(tanhf(acc[r] + bv));
  }
}

// ---------------- logits via MFMA + copy-compose + sparse clear ----------------
__device__ __forceinline__ float dec_f(unsigned e) {
  return (e & 0x80000000u) ? __uint_as_float(e ^ 0x80000000u) : __uint_as_float(~e);
}
__global__ __launch_bounds__(256) void k_logits_mfma(
    const ushort* __restrict__ hid, const ushort* __restrict__ pW2b,
    const float* __restrict__ pb2, unsigned* __restrict__ ubuf,
    float* __restrict__ outp, int s)
{
  const int wave = threadIdx.x >> 6, lane = threadIdx.x & 63;
  const int lr = lane & 15, kg = lane >> 4;
  const int base = blockIdx.x*256 + wave*64;
  f32x4 acc[4] = {};
  const ushort* arow = hid + lr*1024 + kg*8;
  for (int k0 = 0; k0 < 1024; k0 += 32) {
    bf16x8 af = *(const bf16x8*)(arow + k0);
    #pragma unroll
    for (int nt = 0; nt < 4; ++nt) {
      bf16x8 bf = *(const bf16x8*)&pW2b[(long)(base + nt*16 + lr)*1024 + k0 + kg*8];
      acc[nt] = __builtin_amdgcn_mfma_f32_16x16x32_bf16(af, bf, acc[nt], 0, 0, 0);
    }
  }
  #pragma unroll
  for (int nt = 0; nt < 4; ++nt) {
    int v = base + nt*16 + lr;
    if (v >= NEXT) continue;
    #pragma unroll
    for (int r = 0; r < 4; ++r) {
      int b = kg*4 + r;
      unsigned u = ubuf[(long)b*NEXT + v];
      float o = u ? dec_f(u) : 0.f;
      float e = (v < NV) ? (acc[nt][r] + pb2[v]) : 0.f;
      float lg = e + o;
      if (lg == 0.f) lg = NEG_INF;
      outp[((long)b*NTT + s)*NEXT + v] = lg;
      if (u) ubuf[(long)b*NEXT + v] = 0u;
    }
  }
}

// ---------------- final coverage-loss scalar ----------------
__global__ void k_covout(const float* __restrict__ covacc, float* __restrict__ outp)
{
  outp[(long)NB*NTT*NEXT] = covacc[0] * (1.0f/(NB*NTT));
}

// ==================== host ====================
extern "C" void kernel_launch(void* const* d_in, const int* in_sizes, int n_in,
                              void* d_out, int out_size, void* d_ws, size_t ws_size,
                              hipStream_t stream) {
  (void)in_sizes; (void)n_in; (void)out_size; (void)ws_size;
  const float* enc_emb = (const float*)d_in[0];
  const float* ans_emb = (const float*)d_in[1];
  const float* dec_emb = (const float*)d_in[2];
  const float* eWi0 = (const float*)d_in[3];
  const float* eWh0 = (const float*)d_in[4];
  const float* ebi0 = (const float*)d_in[5];
  const float* ebh0 = (const float*)d_in[6];
  const float* eWi1 = (const float*)d_in[7];
  const float* eWh1 = (const float*)d_in[8];
  const float* ebi1 = (const float*)d_in[9];
  const float* ebh1 = (const float*)d_in[10];
  const float* trans_W = (const float*)d_in[11];
  const float* trans_b = (const float*)d_in[12];
  const float* upd_W = (const float*)d_in[13];
  const float* gate_W = (const float*)d_in[14];
  const float* dWi0 = (const float*)d_in[15];
  const float* dWh0 = (const float*)d_in[16];
  const float* dbi0 = (const float*)d_in[17];
  const float* dbh0 = (const float*)d_in[18];
  const float* dWi1 = (const float*)d_in[19];
  const float* dWh1 = (const float*)d_in[20];
  const float* dbi1 = (const float*)d_in[21];
  const float* dbh1 = (const float*)d_in[22];
  const float* dtrans_W = (const float*)d_in[23];
  const float* dtrans_b = (const float*)d_in[24];
  const float* pW1 = (const float*)d_in[25];
  const float* pb1 = (const float*)d_in[26];
  const float* pW2 = (const float*)d_in[27];
  const float* pb2 = (const float*)d_in[28];
  const int* input_s = (const int*)d_in[29];
  const int* ext_ids = (const int*)d_in[30];
  const int* input_q = (const int*)d_in[31];
  const int* input_a = (const int*)d_in[32];
  float* out = (float*)d_out;

  float* ws = (float*)d_ws;
  size_t off = 0;
  auto alloc = [&](size_t n) { float* p = ws + off; off += (n + 3) & ~(size_t)3; return p; };
  auto alloch = [&](size_t nh) { return (ushort*)alloc((nh + 1) / 2); };

  // --- small persistent ---
  ushort* hpp  = alloch(2ull*2*NB*HENC);      // 32768 ush
  int*   bar   = (int*)alloc(8);
  float* covacc= alloc(4);
  float* cov   = alloc(NB*TSN);
  unsigned* ubuf = (unsigned*)alloc((size_t)NB*NEXT);
  float* hfin0 = alloc(NB*HD2);
  float* hfin1 = alloc(NB*HD2);
  float* dh0   = alloc(2ull*NB*HD2);
  float* dh1   = alloc(2ull*NB*HD2);
  ushort* h0b  = alloch(2ull*NB*HD2);
  ushort* h1b  = alloch(2ull*NB*HD2);
  ushort* ctxbf= alloch(2ull*NB*HD2);
  ushort* catbf= alloch((size_t)NB*2048);
  ushort* hidbf= alloch((size_t)NB*HD2);

  // --- bf16 weights ---
  ushort* eWi0c   = alloch(2ull*G3E*384);
  ushort* eWi1c   = alloch(2ull*G3E*1024);
  ushort* Whb0    = alloch(2ull*G3E*HENC);
  ushort* Whb1    = alloch(2ull*G3E*HENC);
  ushort* transWb = alloch(1024ull*1024);
  ushort* updWb   = alloch(1024ull*2048);
  ushort* gateWb  = alloch(1024ull*2048);
  ushort* dtransWb= alloch(1024ull*1024);
  ushort* dWi0e   = alloch(3072ull*320);
  ushort* dWi0c   = alloch(3072ull*1024);
  ushort* dWh0b   = alloch(3072ull*1024);
  ushort* dWi1b   = alloch(3072ull*1024);
  ushort* dWh1b   = alloch(3072ull*1024);
  ushort* pW1b    = alloch(1024ull*2048);

  // --- alias region: [GX | X0c | Y0bf | ft] reused later as pW2b (+outpTb in ft zone) ---
  size_t regionStart = off;
  float*  GX   = alloc(2ull*6400*G3E);          // 19,660,800 f
  ushort* X0c  = alloch(6400ull*384);           //  1,228,800 f
  ushort* Y0bf = alloch(6400ull*1024);          //  3,276,800 f
  float*  ft   = alloc(6400ull*HD2);            //  6,553,600 f  (region = 30,720,000 f)
  ushort* pW2b   = (ushort*)(ws + regionStart);             // 25,690,112 f
  ushort* outpTb = (ushort*)(ws + regionStart + 26000000);  //  3,670,016 f (inside ft zone; used before ft)

  // --- big buffers ---
  ushort* outpbf = alloch(6400ull*HD2);
  ushort* memsbf = alloch(6400ull*HD2);
  float*  scratchC = alloc(6400ull*HD2);
  float*  energ  = alloc((size_t)NB*TSN*TSN);
  ushort* scoresb= alloch((size_t)NB*TSN*448);
  ushort* ctx_bf = alloch(6400ull*HD2);
  ushort* memd_bf= alloch(6400ull*HD2);
  ushort* encbf  = alloch(6400ull*HD2);
  ushort* embqb  = alloch(512ull*320);
  float*  embGX  = alloc(512ull*G3D);

  // ---------------- one-time casts ----------------
  k_embed_bf<<<9600, 256, 0, stream>>>(enc_emb, ans_emb, input_s, input_a, X0c);
  k_castw<<<4608, 256, 0, stream>>>(eWi0, eWi0c, 3072, 3072ull*384, 332, 384, 332, 0);
  k_castw<<<12288, 256, 0, stream>>>(eWi1, eWi1c, 3072, 3072ull*1024, 1024, 1024, 1024, 0);
  k_castw<<<6144, 256, 0, stream>>>(eWh0, Whb0, 3072, 3072ull*512, 512, 512, 512, 0);
  k_castw<<<6144, 256, 0, stream>>>(eWh1, Whb1, 3072, 3072ull*512, 512, 512, 512, 0);
  k_castw<<<4096, 256, 0, stream>>>(trans_W, transWb, 1024, 1024ull*1024, 1024, 1024, 1024, 0);
  k_castw<<<8192, 256, 0, stream>>>(upd_W,  updWb,  1024, 1024ull*2048, 2048, 2048, 2048, 0);
  k_castw<<<8192, 256, 0, stream>>>(gate_W, gateWb, 1024, 1024ull*2048, 2048, 2048, 2048, 0);
  k_castw<<<4096, 256, 0, stream>>>(dtrans_W, dtransWb, 1024, 1024ull*1024, 1024, 1024, 1024, 0);
  k_castw<<<3840, 256, 0, stream>>>(dWi0, dWi0e, 3072, 3072ull*320, 300, 320, 1324, 0);
  k_castw<<<12288, 256, 0, stream>>>(dWi0, dWi0c, 3072, 3072ull*1024, 1024, 1024, 1324, 300);
  k_castw<<<12288, 256, 0, stream>>>(dWh0, dWh0b, 3072, 3072ull*1024, 1024, 1024, 1024, 0);
  k_castw<<<12288, 256, 0, stream>>>(dWi1, dWi1b, 3072, 3072ull*1024, 1024, 1024, 1024, 0);
  k_castw<<<12288, 256, 0, stream>>>(dWh1, dWh1b, 3072, 3072ull*1024, 1024, 1024, 1024, 0);
  k_castw<<<8192, 256, 0, stream>>>(pW1, pW1b, 1024, 1024ull*2048, 2048, 2048, 2048, 0);

  hipMemsetAsync(bar, 0, 32, stream);

  // ---------------- encoder layer 0 ----------------
  k_mfma_nt<<<dim3(100,24,2), 256, 0, stream>>>(X0c, eWi0c, ebi0, GX, nullptr,
      6400, G3E, 384, 384, 384, G3E, 0, (long)G3E*384, 6400ull*G3E, G3E, 0, 0);
  hipMemsetAsync(hpp, 0, 2ull*2*NB*HENC*2, stream);
  k_scan_mfma<<<16, 256, 0, stream>>>(GX, GX + 6400ull*G3E, Whb0, ebh0,
      nullptr, Y0bf, 0, hfin0, hpp, bar, bar + 1);
  // ---------------- encoder layer 1 ----------------
  k_mfma_nt<<<dim3(100,24,2), 256, 0, stream>>>(Y0bf, eWi1c, ebi1, GX, nullptr,
      6400, G3E, 1024, 1024, 1024, G3E, 0, (long)G3E*1024, 6400ull*G3E, G3E, 0, 0);
  hipMemsetAsync(hpp, 0, 2ull*2*NB*HENC*2, stream);
  k_scan_mfma<<<16, 256, 0, stream>>>(GX, GX + 6400ull*G3E, Whb1, ebh1,
      nullptr, outpbf, 1, hfin1, hpp, bar + 2, bar + 3);

  // ---------------- self/answer attention ----------------
  k_mfma_nt<<<dim3(100,16,1), 256, 0, stream>>>(outpbf, transWb, trans_b, scratchC, memsbf,
      6400, HD2, 1024, 1024, 1024, HD2, 0, 0, 0, 0, 0, 0);
  k_mfma_nt<<<dim3(7,7,16), 256, 0, stream>>>(outpbf, memsbf, nullptr, energ, nullptr,
      TSN, TSN, 1024, 1024, 1024, TSN, (long)TSN*1024, (long)TSN*1024, (long)TSN*TSN, 0, 0, 0);
  k_softmax_bf<<<NB*TSN, 256, 0, stream>>>(energ, scoresb);
  k_transpose_hh<<<dim3(14,32,16), 256, 0, stream>>>(outpbf, outpTb);
  k_mfma_nt<<<dim3(7,16,16), 256, 0, stream>>>(scoresb, outpTb, nullptr, scratchC, ctx_bf,
      TSN, HD2, 448, 448, 448, HD2, (long)TSN*448, (long)HD2*448, (long)TSN*HD2, 0, 0, 0);
  k_mfma_nt<<<dim3(100,16,1), 256, 0, stream>>>(outpbf, updWb,        nullptr, ft, nullptr,
      6400, HD2, 1024, 1024, 2048, HD2, 0, 0, 0, 0, 0, 0);
  k_mfma_nt<<<dim3(100,16,1), 256, 0, stream>>>(ctx_bf, updWb + 1024, nullptr, ft, nullptr,
      6400, HD2, 1024, 1024, 2048, HD2, 0, 0, 0, 0, 1, 1);
  k_mfma_nt<<<dim3(100,16,1), 256, 0, stream>>>(outpbf, gateWb,       nullptr, scratchC, nullptr,
      6400, HD2, 1024, 1024, 2048, HD2, 0, 0, 0, 0, 0, 0);
  k_mfma_nt<<<dim3(100,16,1), 256, 0, stream>>>(ctx_bf, gateWb + 1024, nullptr, scratchC, nullptr,
      6400, HD2, 1024, 1024, 2048, HD2, 0, 0, 0, 0, 1, 2);
  k_ansatt2<<<64, 256, 0, stream>>>(memsbf, ft, scratchC, outpbf, input_a, encbf);
  // region now dead: cast pW2
  k_castw<<<200704, 256, 0, stream>>>(pW2, pW2b, NV, (long)NVP*1024, 1024, 1024, 1024, 0);
  k_mfma_nt<<<dim3(100,16,1), 256, 0, stream>>>(encbf, dtransWb, dtrans_b, scratchC, memd_bf,
      6400, HD2, 1024, 1024, 1024, HD2, 0, 0, 0, 0, 0, 0);

  // ---------------- decoder precompute ----------------
  k_embq_bf<<<640, 256, 0, stream>>>(dec_emb, input_q, embqb);
  k_mfma_nt<<<dim3(8,48,1), 256, 0, stream>>>(embqb, dWi0e, dbi0, embGX, nullptr,
      NTT*NB, G3D, 320, 320, 320, G3D, 0, 0, 0, 0, 0, 0);

  hipMemsetAsync(cov, 0, (size_t)NB*TSN*4, stream);
  hipMemsetAsync(covacc, 0, 4, stream);
  hipMemsetAsync(ubuf, 0, (size_t)NB*NEXT*4, stream);
  hipMemsetAsync(ctxbf, 0, (size_t)NB*HD2*2, stream);
  hipMemcpyAsync(dh0, hfin0, (size_t)NB*HD2*4, hipMemcpyDeviceToDevice, stream);
  hipMemcpyAsync(dh1, hfin1, (size_t)NB*HD2*4, hipMemcpyDeviceToDevice, stream);
  k_cast<<<64, 256, 0, stream>>>(hfin0, h0b, 16384);
  k_cast<<<64, 256, 0, stream>>>(hfin1, h1b, 16384);

  // ---------------- decoder steps ----------------
  for (int s = 0; s < NTT; ++s) {
    int cur = s & 1, nxt = cur ^ 1;
    float* h0c = dh0 + (size_t)cur*NB*HD2;  float* h0n = dh0 + (size_t)nxt*NB*HD2;
    float* h1c = dh1 + (size_t)cur*NB*HD2;  float* h1n = dh1 + (size_t)nxt*NB*HD2;
    ushort* h0bc = h0b + (size_t)cur*NB*HD2; ushort* h0bn = h0b + (size_t)nxt*NB*HD2;
    ushort* h1bc = h1b + (size_t)cur*NB*HD2; ushort* h1bn = h1b + (size_t)nxt*NB*HD2;
    ushort* ctxc = ctxbf + (size_t)cur*NB*HD2; ushort* ctxn = ctxbf + (size_t)nxt*NB*HD2;

    k_gru_dec<<<16, 256, 0, stream>>>(ctxc, dWi0c, h0bc, dWh0b,
        embGX + (size_t)s*NB*G3D, nullptr, dbh0, h0c, h0n, h0bn, nullptr);
    k_gru_dec<<<16, 256, 0, stream>>>(h0bn, dWi1b, h1bc, dWh1b,
        nullptr, dbi1, dbh1, h1c, h1n, h1bn, catbf);
    k_dec_attn2<<<NB, 1024, 0, stream>>>(h1bn, memd_bf, ext_ids,
        cov, ubuf, covacc, ctxn, catbf);
    k_hid<<<16, 256, 0, stream>>>(catbf, pW1b, pb1, hidbf);
    k_logits_mfma<<<196, 256, 0, stream>>>(hidbf, pW2b, pb2, ubuf, out, s);
  }
  k_covout<<<1, 1, 0, stream>>>(covacc, out);
}

// Round 4
// 10435.102 us; speedup vs baseline: 3.8162x; 1.4905x over previous
//
#include <hip/hip_runtime.h>
#include <stdint.h>

#define TSN 400
#define NB 16
#define HENC 512
#define HD2 1024
#define G3E 1536
#define G3D 3072
#define EMBD 300
#define AEMB 32
#define NV 50000
#define NEXT 50100
#define NVP 50176
#define NTT 32
#define NEG_INF (-1.0e12f)

typedef __attribute__((ext_vector_type(8))) short bf16x8;
typedef __attribute__((ext_vector_type(4))) float f32x4;

__device__ __forceinline__ ushort f2bf(float f) {
  unsigned u = __float_as_uint(f);
  unsigned r = (u + 0x7fffu + ((u >> 16) & 1u)) >> 16;
  return (ushort)r;
}
__device__ __forceinline__ float bf2f(ushort h) {
  return __uint_as_float((unsigned)h << 16);
}

// ---------------- embeddings -> bf16, padded K=384 ----------------
__global__ __launch_bounds__(256) void k_embed_bf(
    const float* __restrict__ enc_emb, const float* __restrict__ ans_emb,
    const int* __restrict__ input_s, const int* __restrict__ input_a,
    ushort* __restrict__ X0)
{
  long i = (long)blockIdx.x*256 + threadIdx.x;
  if (i >= (long)TSN*NB*384) return;
  int c = (int)(i % 384);
  long r = i / 384;
  int b = (int)(r % NB);
  int t = (int)(r / NB);
  float v = 0.f;
  if (c < EMBD) v = enc_emb[(long)input_s[b*TSN + t]*EMBD + c];
  else if (c < 332) v = ans_emb[(long)input_a[b*TSN + t]*AEMB + (c - EMBD)];
  X0[i] = f2bf(v);
}

// ---------------- decoder emb -> bf16, padded K=320 ----------------
__global__ __launch_bounds__(256) void k_embq_bf(
    const float* __restrict__ dec_emb, const int* __restrict__ input_q,
    ushort* __restrict__ EQ)
{
  long i = (long)blockIdx.x*256 + threadIdx.x;
  if (i >= (long)NTT*NB*320) return;
  int c = (int)(i % 320);
  long r = i / 320;
  int b = (int)(r % NB);
  int s = (int)(r / NB);
  EQ[i] = (c < EMBD) ? f2bf(dec_emb[(long)input_q[b*33 + s]*EMBD + c]) : (ushort)0;
}

// ---------------- weight cast with pad ----------------
__global__ __launch_bounds__(256) void k_castw(
    const float* __restrict__ src, ushort* __restrict__ dst,
    int Nsrc, long total, int Ksrc, int Kdst, int ldsrc, int coloff)
{
  long i = (long)blockIdx.x*256 + threadIdx.x;
  if (i >= total) return;
  int k = (int)(i % Kdst);
  long n = i / Kdst;
  float v = (n < Nsrc && k < Ksrc) ? src[n*ldsrc + coloff + k] : 0.f;
  dst[i] = f2bf(v);
}

// ---------------- plain cast fp32 -> bf16 ----------------
__global__ __launch_bounds__(256) void k_cast(
    const float* __restrict__ s, ushort* __restrict__ d, long n)
{
  long i = (long)blockIdx.x*256 + threadIdx.x;
  if (i >= n) return;
  d[i] = f2bf(s[i]);
}

// ---------------- bf16 batched transpose with K-pad: out[b][c][r(448)] ----------------
__global__ __launch_bounds__(256) void k_transpose_hh(
    const ushort* __restrict__ in, ushort* __restrict__ out)
{
  __shared__ ushort tb[32][33];
  int b = blockIdx.z;
  int r0 = blockIdx.x*32, c0 = blockIdx.y*32;
  int tx = threadIdx.x & 31, ty = threadIdx.x >> 5;
  #pragma unroll
  for (int i = 0; i < 32; i += 8) {
    int r = r0 + ty + i, c = c0 + tx;
    tb[ty+i][tx] = (r < TSN) ? in[((long)b*TSN + r)*1024 + c] : (ushort)0;
  }
  __syncthreads();
  #pragma unroll
  for (int i = 0; i < 32; i += 8) {
    int c = c0 + ty + i, r = r0 + tx;
    out[((long)b*1024 + c)*448 + r] = tb[tx][ty+i];
  }
}

// ---------------- MFMA GEMM ----------------
__global__ __launch_bounds__(256) void k_mfma_nt(
    const ushort* __restrict__ Ab, const ushort* __restrict__ Wb,
    const float* __restrict__ bias, float* __restrict__ Cb, ushort* __restrict__ C2b,
    int M, int N, int K, int lda, int ldw, int ldc,
    long sA, long sW, long sC, long sBias, int accum, int act)
{
  __shared__ ushort As[64][72];
  __shared__ ushort Ws[64][72];
  const ushort* A = Ab + (long)blockIdx.z * sA;
  const ushort* W = Wb + (long)blockIdx.z * sW;
  float* C = Cb + (long)blockIdx.z * sC;
  const float* bi = bias ? bias + (long)blockIdx.z * sBias : nullptr;
  const int m0 = blockIdx.x*64, n0 = blockIdx.y*64;
  const int tid = threadIdx.x;
  const int wave = tid >> 6, lane = tid & 63;
  const int wm = wave >> 1, wn = wave & 1;
  const int lr = lane & 15, kg = lane >> 4;
  f32x4 acc[2][2] = {};
  for (int k0 = 0; k0 < K; k0 += 64) {
    __syncthreads();
    #pragma unroll
    for (int it = 0; it < 2; ++it) {
      int sidx = tid + it*256;
      int r = sidx >> 3, c = (sidx & 7)*8;
      bf16x8 av = {};
      bf16x8 wv = {};
      if (m0 + r < M) av = *(const bf16x8*)&A[(long)(m0+r)*lda + k0 + c];
      if (n0 + r < N) wv = *(const bf16x8*)&W[(long)(n0+r)*ldw + k0 + c];
      *(bf16x8*)&As[r][c] = av;
      *(bf16x8*)&Ws[r][c] = wv;
    }
    __syncthreads();
    #pragma unroll
    for (int kk = 0; kk < 2; ++kk) {
      bf16x8 af[2], bf[2];
      #pragma unroll
      for (int mt = 0; mt < 2; ++mt)
        af[mt] = *(const bf16x8*)&As[wm*32 + mt*16 + lr][kk*32 + kg*8];
      #pragma unroll
      for (int nt = 0; nt < 2; ++nt)
        bf[nt] = *(const bf16x8*)&Ws[wn*32 + nt*16 + lr][kk*32 + kg*8];
      #pragma unroll
      for (int mt = 0; mt < 2; ++mt)
        #pragma unroll
        for (int nt = 0; nt < 2; ++nt)
          acc[mt][nt] = __builtin_amdgcn_mfma_f32_16x16x32_bf16(af[mt], bf[nt], acc[mt][nt], 0, 0, 0);
    }
  }
  #pragma unroll
  for (int mt = 0; mt < 2; ++mt) {
    #pragma unroll
    for (int r = 0; r < 4; ++r) {
      int m = m0 + wm*32 + mt*16 + kg*4 + r;
      if (m >= M) continue;
      #pragma unroll
      for (int nt = 0; nt < 2; ++nt) {
        int n = n0 + wn*32 + nt*16 + lr;
        if (n >= N) continue;
        float v = acc[mt][nt][r];
        if (accum) v += C[(long)m*ldc + n];
        if (bi)    v += bi[n];
        if (act == 1) v = tanhf(v);
        else if (act == 2) v = 1.f/(1.f + expf(-v));
        C[(long)m*ldc + n] = v;
        if (C2b) C2b[(long)blockIdx.z*sC + (long)m*ldc + n] = f2bf(v);
      }
    }
  }
}

// ---------------- persistent MFMA bidirectional GRU scan ----------------
// 16 blocks x 256. Weights preloaded to registers (192 VGPR). One distributed
// single-hop barrier per step; gx prefetched one step ahead.
__global__ __launch_bounds__(256, 1) void k_scan_mfma(
    const float* __restrict__ GXf, const float* __restrict__ GXb,
    const ushort* __restrict__ Whb,   // [2][1536][512] bf16
    const float* __restrict__ bh,     // [2][1536]
    ushort* __restrict__ Ybf, int bmajor,
    float* __restrict__ hfin,
    ushort* __restrict__ hpp,         // [2 ping][2 dir][16][512] bf16
    int* __restrict__ slots)          // [16]
{
  const int bid = blockIdx.x;
  const int wg = bid*4 + (threadIdx.x >> 6);
  const int lane = threadIdx.x & 63;
  const int lr = lane & 15, kg = lane >> 4;
  const int dir = wg >> 5, jt = wg & 31;
  const int j = jt*16 + lr;
  const ushort* Wp0 = Whb + ((long)(dir*G3E + j)        << 9) + kg*8;
  const ushort* Wp1 = Whb + ((long)(dir*G3E + 512 + j)  << 9) + kg*8;
  const ushort* Wp2 = Whb + ((long)(dir*G3E + 1024 + j) << 9) + kg*8;
  bf16x8 W0[16], W1[16], W2[16];
  #pragma unroll
  for (int i = 0; i < 16; ++i) {
    W0[i] = *(const bf16x8*)(Wp0 + i*32);
    W1[i] = *(const bf16x8*)(Wp1 + i*32);
    W2[i] = *(const bf16x8*)(Wp2 + i*32);
  }
  const float bh0 = bh[dir*G3E + j];
  const float bh1 = bh[dir*G3E + 512 + j];
  const float bh2 = bh[dir*G3E + 1024 + j];
  const float* GX = dir ? GXb : GXf;
  float hreg[4] = {0.f, 0.f, 0.f, 0.f};
  float g0[4], g1[4], g2[4];
  {
    const int t0 = dir ? (TSN - 1) : 0;
    const float* gxp = GX + (long)t0*NB*G3E + j;
    #pragma unroll
    for (int r = 0; r < 4; ++r) {
      const float* g = gxp + (long)(kg*4 + r)*G3E;
      g0[r] = g[0]; g1[r] = g[512]; g2[r] = g[1024];
    }
  }
  for (int s = 0; s < TSN; ++s) {
    const int cur = s & 1;
    const ushort* hA = hpp + (((cur<<1) + dir)*16 + lr)*512 + kg*8;
    bf16x8 hf[16];
    #pragma unroll
    for (int i = 0; i < 16; ++i) hf[i] = *(const bf16x8*)(hA + i*32);
    f32x4 a0 = {}, a1 = {}, a2 = {};
    #pragma unroll
    for (int i = 0; i < 16; ++i) {
      a0 = __builtin_amdgcn_mfma_f32_16x16x32_bf16(hf[i], W0[i], a0, 0, 0, 0);
      a1 = __builtin_amdgcn_mfma_f32_16x16x32_bf16(hf[i], W1[i], a1, 0, 0, 0);
      a2 = __builtin_amdgcn_mfma_f32_16x16x32_bf16(hf[i], W2[i], a2, 0, 0, 0);
    }
    const int t = dir ? (TSN - 1 - s) : s;
    ushort* hO = hpp + (((cur^1)<<1) + dir)*16*512;
    #pragma unroll
    for (int r = 0; r < 4; ++r) {
      int b = kg*4 + r;
      float rr = 1.f/(1.f + expf(-(g0[r] + a0[r] + bh0)));
      float zz = 1.f/(1.f + expf(-(g1[r] + a1[r] + bh1)));
      float nn = tanhf(g2[r] + rr*(a2[r] + bh2));
      float hn = (1.f - zz)*nn + zz*hreg[r];
      hreg[r] = hn;
      hO[b*512 + j] = f2bf(hn);
      long yi = bmajor ? ((long)b*TSN + t)*1024 + dir*512 + j
                       : ((long)t*NB + b)*1024 + dir*512 + j;
      Ybf[yi] = f2bf(hn);
      if (s == TSN - 1) hfin[b*1024 + dir*512 + j] = hn;
    }
    if (s + 1 < TSN) {
      // prefetch next gx (hidden behind barrier wait)
      const int tn = dir ? (TSN - 2 - s) : (s + 1);
      const float* gxp = GX + (long)tn*NB*G3E + j;
      #pragma unroll
      for (int r = 0; r < 4; ++r) {
        const float* g = gxp + (long)(kg*4 + r)*G3E;
        g0[r] = g[0]; g1[r] = g[512]; g2[r] = g[1024];
      }
      // distributed single-hop barrier
      __threadfence();
      __syncthreads();
      if (threadIdx.x == 0)
        __hip_atomic_store(&slots[bid], s + 1, __ATOMIC_RELEASE, __HIP_MEMORY_SCOPE_AGENT);
      if (threadIdx.x < 16) {
        while (__hip_atomic_load(&slots[threadIdx.x], __ATOMIC_ACQUIRE, __HIP_MEMORY_SCOPE_AGENT) < s + 1)
          __builtin_amdgcn_s_sleep(1);
      }
      __syncthreads();
    }
  }
}

// ---------------- row softmax f32 -> bf16 (pad to 448) ----------------
__global__ __launch_bounds__(256) void k_softmax_bf(
    const float* __restrict__ E, ushort* __restrict__ S)
{
  long row = blockIdx.x;
  const float* x = E + row*TSN;
  ushort* o = S + row*448;
  int tid = threadIdx.x;
  float v0 = (tid < TSN) ? x[tid] : -INFINITY;
  float v1 = (tid + 256 < TSN) ? x[tid + 256] : -INFINITY;
  __shared__ float red[256];
  red[tid] = fmaxf(v0, v1); __syncthreads();
  for (int oo = 128; oo; oo >>= 1) { if (tid < oo) red[tid] = fmaxf(red[tid], red[tid+oo]); __syncthreads(); }
  float m = red[0]; __syncthreads();
  float e0 = (tid < TSN) ? expf(v0 - m) : 0.f;
  float e1 = (tid + 256 < TSN) ? expf(v1 - m) : 0.f;
  red[tid] = e0 + e1; __syncthreads();
  for (int oo = 128; oo; oo >>= 1) { if (tid < oo) red[tid] += red[tid+oo]; __syncthreads(); }
  float inv = 1.f/red[0];
  if (tid < 192) o[tid + 256] = (tid + 256 < TSN) ? f2bf(e1*inv) : (ushort)0;
  o[tid] = f2bf(e0*inv);
}

// ---------------- fused selfcomb + answer attention -> encbf ----------------
__global__ __launch_bounds__(256) void k_ansatt2(
    const ushort* __restrict__ memsb, const float* __restrict__ ft,
    const float* __restrict__ gt, const ushort* __restrict__ outpb,
    const int* __restrict__ input_a, ushort* __restrict__ encb)
{
  int b = blockIdx.x >> 2;
  int d = (blockIdx.x & 3)*256 + threadIdx.x;
  __shared__ int ia[TSN];
  for (int i = threadIdx.x; i < TSN; i += 256) ia[i] = input_a[b*TSN + i];
  __syncthreads();
  float m = -INFINITY;
  #pragma unroll 4
  for (int t = 0; t < TSN; ++t) {
    float v = bf2f(memsb[((long)b*TSN + t)*1024 + d]);
    float e = ia[t] ? v*v : v;
    m = fmaxf(m, e);
  }
  float ssum = 0.f;
  #pragma unroll 4
  for (int t = 0; t < TSN; ++t) {
    float v = bf2f(memsb[((long)b*TSN + t)*1024 + d]);
    float e = ia[t] ? v*v : v;
    ssum += expf(e - m);
  }
  float inv = 1.f/ssum;
  #pragma unroll 4
  for (int t = 0; t < TSN; ++t) {
    long idx = ((long)b*TSN + t)*1024 + d;
    float v = bf2f(memsb[idx]);
    float e = ia[t] ? v*v : v;
    float gg = gt[idx];
    float selfo = gg*ft[idx] + (1.f - gg)*bf2f(outpb[idx]);
    encb[idx] = f2bf(selfo + expf(e - m)*inv*v);
  }
}

// ---------------- decoder GRU layer ----------------
__global__ __launch_bounds__(256) void k_gru_dec(
    const ushort* __restrict__ A1, const ushort* __restrict__ W1,
    const ushort* __restrict__ A2, const ushort* __restrict__ W2,
    const float* __restrict__ gxadd, const float* __restrict__ bi,
    const float* __restrict__ bh,
    const float* __restrict__ hprev, float* __restrict__ hout,
    ushort* __restrict__ houtb, ushort* __restrict__ catb)
{
  const int wg = blockIdx.x*4 + (threadIdx.x >> 6);
  const int lane = threadIdx.x & 63;
  const int lr = lane & 15, kg = lane >> 4;
  const int j = wg*16 + lr;
  const ushort* w1p0 = W1 + ((long)(j)        << 10) + kg*8;
  const ushort* w1p1 = W1 + ((long)(1024 + j) << 10) + kg*8;
  const ushort* w1p2 = W1 + ((long)(2048 + j) << 10) + kg*8;
  const ushort* w2p0 = W2 + ((long)(j)        << 10) + kg*8;
  const ushort* w2p1 = W2 + ((long)(1024 + j) << 10) + kg*8;
  const ushort* w2p2 = W2 + ((long)(2048 + j) << 10) + kg*8;
  const ushort* a1p = A1 + lr*1024 + kg*8;
  const ushort* a2p = A2 + lr*1024 + kg*8;
  f32x4 x0 = {}, x1 = {}, x2 = {}, h0 = {}, h1 = {}, h2 = {};
  #pragma unroll 4
  for (int k0 = 0; k0 < 1024; k0 += 32) {
    bf16x8 a1v = *(const bf16x8*)(a1p + k0);
    bf16x8 a2v = *(const bf16x8*)(a2p + k0);
    x0 = __builtin_amdgcn_mfma_f32_16x16x32_bf16(a1v, *(const bf16x8*)(w1p0 + k0), x0, 0, 0, 0);
    x1 = __builtin_amdgcn_mfma_f32_16x16x32_bf16(a1v, *(const bf16x8*)(w1p1 + k0), x1, 0, 0, 0);
    x2 = __builtin_amdgcn_mfma_f32_16x16x32_bf16(a1v, *(const bf16x8*)(w1p2 + k0), x2, 0, 0, 0);
    h0 = __builtin_amdgcn_mfma_f32_16x16x32_bf16(a2v, *(const bf16x8*)(w2p0 + k0), h0, 0, 0, 0);
    h1 = __builtin_amdgcn_mfma_f32_16x16x32_bf16(a2v, *(const bf16x8*)(w2p1 + k0), h1, 0, 0, 0);
    h2 = __builtin_amdgcn_mfma_f32_16x16x32_bf16(a2v, *(const bf16x8*)(w2p2 + k0), h2, 0, 0, 0);
  }
  float bi0 = bi ? bi[j] : 0.f, bi1 = bi ? bi[1024 + j] : 0.f, bi2 = bi ? bi[2048 + j] : 0.f;
  float bh0 = bh[j], bh1 = bh[1024 + j], bh2 = bh[2048 + j];
  #pragma unroll
  for (int r = 0; r < 4; ++r) {
    int b = kg*4 + r;
    float gxa0 = gxadd ? gxadd[(long)b*G3D + j]        : 0.f;
    float gxa1 = gxadd ? gxadd[(long)b*G3D + 1024 + j] : 0.f;
    float gxa2 = gxadd ? gxadd[(long)b*G3D + 2048 + j] : 0.f;
    float gx0 = x0[r] + gxa0 + bi0;
    float gx1 = x1[r] + gxa1 + bi1;
    float gx2 = x2[r] + gxa2 + bi2;
    float gh0 = h0[r] + bh0, gh1 = h1[r] + bh1, gh2 = h2[r] + bh2;
    float rr = 1.f/(1.f + expf(-(gx0 + gh0)));
    float zz = 1.f/(1.f + expf(-(gx1 + gh1)));
    float nn = tanhf(gx2 + rr*gh2);
    float hp = hprev[b*1024 + j];
    float hn = (1.f - zz)*nn + zz*hp;
    hout[b*1024 + j] = hn;
    houtb[b*1024 + j] = f2bf(hn);
    if (catb) catb[(long)b*2048 + j] = f2bf(hn);
  }
}

// ---------------- fused decoder attention: energy + cov-softmax + ctx; saves cov_e ----------------
__global__ __launch_bounds__(1024) void k_dec_attn2(
    const ushort* __restrict__ h1b, const ushort* __restrict__ memdb,
    float* __restrict__ cov, float* __restrict__ covOut, float* __restrict__ covacc,
    ushort* __restrict__ ctxn, ushort* __restrict__ catb)
{
  const int b = blockIdx.x, tid = threadIdx.x;
  const int wv = tid >> 6, ln = tid & 63;
  __shared__ float sc[TSN];
  __shared__ float at[TSN];
  __shared__ float red[1024];
  float hreg[16];
  {
    bf16x8 hv0 = *(const bf16x8*)&h1b[b*1024 + ln*16];
    bf16x8 hv1 = *(const bf16x8*)&h1b[b*1024 + ln*16 + 8];
    #pragma unroll
    for (int e = 0; e < 8; ++e) { hreg[e] = bf2f((ushort)hv0[e]); hreg[8+e] = bf2f((ushort)hv1[e]); }
  }
  for (int t = wv; t < TSN; t += 16) {
    const ushort* row = memdb + ((long)b*TSN + t)*1024 + ln*16;
    bf16x8 r0 = *(const bf16x8*)row;
    bf16x8 r1 = *(const bf16x8*)(row + 8);
    float p = 0.f;
    #pragma unroll
    for (int e = 0; e < 8; ++e) p += hreg[e]*bf2f((ushort)r0[e]) + hreg[8+e]*bf2f((ushort)r1[e]);
    #pragma unroll
    for (int off = 32; off; off >>= 1) p += __shfl_xor(p, off);
    if (ln == 0) sc[t] = p;
  }
  __syncthreads();
  float ce = -INFINITY, co = 0.f;
  if (tid < TSN) { co = cov[b*TSN + tid]; ce = sc[tid]*(1.f - co); }
  red[tid] = ce; __syncthreads();
  for (int o = 512; o; o >>= 1) { if (tid < o) red[tid] = fmaxf(red[tid], red[tid+o]); __syncthreads(); }
  float m = red[0]; __syncthreads();
  float ex = (tid < TSN) ? expf(ce - m) : 0.f;
  red[tid] = ex; __syncthreads();
  for (int o = 512; o; o >>= 1) { if (tid < o) red[tid] += red[tid+o]; __syncthreads(); }
  float inv = 1.f/red[0]; __syncthreads();
  float closs = 0.f;
  if (tid < TSN) {
    float a = ex*inv;
    at[tid] = a;
    cov[b*TSN + tid] = co + a;
    covOut[b*TSN + tid] = ce;
    closs = fminf(a, co);
  }
  red[tid] = closs; __syncthreads();
  for (int o = 512; o; o >>= 1) { if (tid < o) red[tid] += red[tid+o]; __syncthreads(); }
  if (tid == 0) atomicAdd(covacc, red[0]);
  __syncthreads();
  float s = 0.f;
  const ushort* col = memdb + (long)b*TSN*1024 + tid;
  #pragma unroll 8
  for (int t = 0; t < TSN; ++t) s += at[t]*bf2f(col[(long)t*1024]);
  ushort hv = f2bf(s);
  ctxn[b*1024 + tid] = hv;
  catb[(long)b*2048 + 1024 + tid] = hv;
}

// ---------------- hid = tanh(cat @ pW1^T + pb1) -> bf16, MFMA ----------------
__global__ __launch_bounds__(256) void k_hid(
    const ushort* __restrict__ catb, const ushort* __restrict__ W,
    const float* __restrict__ pb1, ushort* __restrict__ hidb)
{
  const int wg = blockIdx.x*4 + (threadIdx.x >> 6);
  const int lane = threadIdx.x & 63;
  const int lr = lane & 15, kg = lane >> 4;
  const int n = wg*16 + lr;
  f32x4 acc = {};
  const ushort* ap = catb + lr*2048 + kg*8;
  const ushort* wp = W + ((long)n << 11) + kg*8;
  #pragma unroll 8
  for (int k0 = 0; k0 < 2048; k0 += 32)
    acc = __builtin_amdgcn_mfma_f32_16x16x32_bf16(*(const bf16x8*)(ap + k0), *(const bf16x8*)(wp + k0), acc, 0, 0, 0);
  float bv = pb1[n];
  #pragma unroll
  for (int r = 0; r < 4; ++r) {
    int b = kg*4 + r;
    hidb[b*1024 + n] = f2bf(tanhf(acc[r] + bv));
  }
}

// ---------------- batched logits: [512 x 1024] @ pW2^T, composed base write ----------------
__global__ __launch_bounds__(256) void k_logits_all(
    const ushort* __restrict__ hidAll,   // [512][1024], row = s*16+b
    const ushort* __restrict__ pW2b,     // [50176][1024]
    const float* __restrict__ pb2,
    float* __restrict__ outp)            // [16][32][50100]
{
  const int wave = threadIdx.x >> 6, lane = threadIdx.x & 63;
  const int lr = lane & 15, kg = lane >> 4;
  const int n0 = blockIdx.x*256 + wave*64;
  const int m0 = blockIdx.y*128;
  f32x4 acc[8][4] = {};
  for (int k0 = 0; k0 < 1024; k0 += 32) {
    bf16x8 bfr[4];
    #pragma unroll
    for (int nt = 0; nt < 4; ++nt)
      bfr[nt] = *(const bf16x8*)&pW2b[(long)(n0 + nt*16 + lr)*1024 + k0 + kg*8];
    #pragma unroll
    for (int mt = 0; mt < 8; ++mt) {
      bf16x8 af = *(const bf16x8*)&hidAll[(long)(m0 + mt*16 + lr)*1024 + k0 + kg*8];
      #pragma unroll
      for (int nt = 0; nt < 4; ++nt)
        acc[mt][nt] = __builtin_amdgcn_mfma_f32_16x16x32_bf16(af, bfr[nt], acc[mt][nt], 0, 0, 0);
    }
  }
  #pragma unroll
  for (int nt = 0; nt < 4; ++nt) {
    int v = n0 + nt*16 + lr;
    if (v >= NEXT) continue;
    float pb = (v < NV) ? pb2[v] : 0.f;
    #pragma unroll
    for (int mt = 0; mt < 8; ++mt) {
      #pragma unroll
      for (int r = 0; r < 4; ++r) {
        int m = m0 + mt*16 + kg*4 + r;
        int s = m >> 4, b = m & 15;
        float e = (v < NV) ? (acc[mt][nt][r] + pb) : 0.f;
        if (e == 0.f) e = NEG_INF;
        outp[((long)b*NTT + s)*NEXT + v] = e;
      }
    }
  }
}

// ---------------- per-step copy-scatter compose (fixes <=6400 positions) ----------------
__device__ __forceinline__ float dec_f(unsigned e) {
  return (e & 0x80000000u) ? __uint_as_float(e ^ 0x80000000u) : __uint_as_float(~e);
}
__global__ __launch_bounds__(512) void k_compose(
    const int* __restrict__ ids, const float* __restrict__ coveAll,
    unsigned* __restrict__ ubuf, float* __restrict__ outp, int s)
{
  int b = blockIdx.x, tid = threadIdx.x;
  int v = 0;
  if (tid < TSN) {
    v = ids[b*TSN + tid];
    float ce = coveAll[((long)s*NB + b)*TSN + tid];
    unsigned bb = __float_as_uint(ce);
    unsigned enc = (bb & 0x80000000u) ? ~bb : (bb | 0x80000000u);
    atomicMax(&ubuf[(long)b*NEXT + v], enc);
  }
  __threadfence();
  __syncthreads();
  if (tid < TSN) {
    unsigned u = __hip_atomic_load(&ubuf[(long)b*NEXT + v], __ATOMIC_RELAXED, __HIP_MEMORY_SCOPE_AGENT);
    float o = dec_f(u);
    long oi = ((long)b*NTT + s)*NEXT + v;
    float e = outp[oi];
    if (e == NEG_INF) e = 0.f;
    float lg = e + o;
    if (lg == 0.f) lg = NEG_INF;
    outp[oi] = lg;
  }
  __syncthreads();
  if (tid < TSN) ubuf[(long)b*NEXT + v] = 0u;
}

// ---------------- final coverage-loss scalar ----------------
__global__ void k_covout(const float* __restrict__ covacc, float* __restrict__ outp)
{
  outp[(long)NB*NTT*NEXT] = covacc[0] * (1.0f/(NB*NTT));
}

// ==================== host ====================
extern "C" void kernel_launch(void* const* d_in, const int* in_sizes, int n_in,
                              void* d_out, int out_size, void* d_ws, size_t ws_size,
                              hipStream_t stream) {
  (void)in_sizes; (void)n_in; (void)out_size; (void)ws_size;
  const float* enc_emb = (const float*)d_in[0];
  const float* ans_emb = (const float*)d_in[1];
  const float* dec_emb = (const float*)d_in[2];
  const float* eWi0 = (const float*)d_in[3];
  const float* eWh0 = (const float*)d_in[4];
  const float* ebi0 = (const float*)d_in[5];
  const float* ebh0 = (const float*)d_in[6];
  const float* eWi1 = (const float*)d_in[7];
  const float* eWh1 = (const float*)d_in[8];
  const float* ebi1 = (const float*)d_in[9];
  const float* ebh1 = (const float*)d_in[10];
  const float* trans_W = (const float*)d_in[11];
  const float* trans_b = (const float*)d_in[12];
  const float* upd_W = (const float*)d_in[13];
  const float* gate_W = (const float*)d_in[14];
  const float* dWi0 = (const float*)d_in[15];
  const float* dWh0 = (const float*)d_in[16];
  const float* dbi0 = (const float*)d_in[17];
  const float* dbh0 = (const float*)d_in[18];
  const float* dWi1 = (const float*)d_in[19];
  const float* dWh1 = (const float*)d_in[20];
  const float* dbi1 = (const float*)d_in[21];
  const float* dbh1 = (const float*)d_in[22];
  const float* dtrans_W = (const float*)d_in[23];
  const float* dtrans_b = (const float*)d_in[24];
  const float* pW1 = (const float*)d_in[25];
  const float* pb1 = (const float*)d_in[26];
  const float* pW2 = (const float*)d_in[27];
  const float* pb2 = (const float*)d_in[28];
  const int* input_s = (const int*)d_in[29];
  const int* ext_ids = (const int*)d_in[30];
  const int* input_q = (const int*)d_in[31];
  const int* input_a = (const int*)d_in[32];
  float* out = (float*)d_out;

  float* ws = (float*)d_ws;
  size_t off = 0;
  auto alloc = [&](size_t n) { float* p = ws + off; off += (n + 15) & ~(size_t)15; return p; };
  auto alloch = [&](size_t nh) { return (ushort*)alloc((nh + 1) / 2); };

  // --- small persistent ---
  ushort* hpp  = alloch(2ull*2*NB*HENC);
  int*   bar   = (int*)alloc(128);   // two 16-slot barrier arrays, separated
  float* covacc= alloc(4);
  float* cov   = alloc(NB*TSN);
  unsigned* ubuf = (unsigned*)alloc((size_t)NB*NEXT);
  float* hfin0 = alloc(NB*HD2);
  float* hfin1 = alloc(NB*HD2);
  float* dh0   = alloc(2ull*NB*HD2);
  float* dh1   = alloc(2ull*NB*HD2);
  ushort* h0b  = alloch(2ull*NB*HD2);
  ushort* h1b  = alloch(2ull*NB*HD2);
  ushort* ctxbf= alloch(2ull*NB*HD2);
  ushort* catbf= alloch((size_t)NB*2048);
  ushort* hidAll = alloch((size_t)NTT*NB*HD2);   // [32][16][1024]
  float* coveAll = alloc((size_t)NTT*NB*TSN);    // [32][16][400]

  // --- bf16 weights ---
  ushort* eWi0c   = alloch(2ull*G3E*384);
  ushort* eWi1c   = alloch(2ull*G3E*1024);
  ushort* Whb0    = alloch(2ull*G3E*HENC);
  ushort* Whb1    = alloch(2ull*G3E*HENC);
  ushort* transWb = alloch(1024ull*1024);
  ushort* updWb   = alloch(1024ull*2048);
  ushort* gateWb  = alloch(1024ull*2048);
  ushort* dtransWb= alloch(1024ull*1024);
  ushort* dWi0e   = alloch(3072ull*320);
  ushort* dWi0c   = alloch(3072ull*1024);
  ushort* dWh0b   = alloch(3072ull*1024);
  ushort* dWi1b   = alloch(3072ull*1024);
  ushort* dWh1b   = alloch(3072ull*1024);
  ushort* pW1b    = alloch(1024ull*2048);

  // --- alias region: [GX | X0c | Y0bf | ft] reused later as pW2b (+outpTb) ---
  size_t regionStart = off;
  float*  GX   = alloc(2ull*6400*G3E);
  ushort* X0c  = alloch(6400ull*384);
  ushort* Y0bf = alloch(6400ull*1024);
  float*  ft   = alloc(6400ull*HD2);
  ushort* pW2b   = (ushort*)(ws + regionStart);
  ushort* outpTb = (ushort*)(ws + regionStart + 26000000);

  // --- big buffers ---
  ushort* outpbf = alloch(6400ull*HD2);
  ushort* memsbf = alloch(6400ull*HD2);
  float*  scratchC = alloc(6400ull*HD2);
  float*  energ  = alloc((size_t)NB*TSN*TSN);
  ushort* scoresb= alloch((size_t)NB*TSN*448);
  ushort* ctx_bf = alloch(6400ull*HD2);
  ushort* memd_bf= alloch(6400ull*HD2);
  ushort* encbf  = alloch(6400ull*HD2);
  ushort* embqb  = alloch(512ull*320);
  float*  embGX  = alloc(512ull*G3D);

  // ---------------- one-time casts ----------------
  k_embed_bf<<<9600, 256, 0, stream>>>(enc_emb, ans_emb, input_s, input_a, X0c);
  k_castw<<<4608, 256, 0, stream>>>(eWi0, eWi0c, 3072, 3072ull*384, 332, 384, 332, 0);
  k_castw<<<12288, 256, 0, stream>>>(eWi1, eWi1c, 3072, 3072ull*1024, 1024, 1024, 1024, 0);
  k_castw<<<6144, 256, 0, stream>>>(eWh0, Whb0, 3072, 3072ull*512, 512, 512, 512, 0);
  k_castw<<<6144, 256, 0, stream>>>(eWh1, Whb1, 3072, 3072ull*512, 512, 512, 512, 0);
  k_castw<<<4096, 256, 0, stream>>>(trans_W, transWb, 1024, 1024ull*1024, 1024, 1024, 1024, 0);
  k_castw<<<8192, 256, 0, stream>>>(upd_W,  updWb,  1024, 1024ull*2048, 2048, 2048, 2048, 0);
  k_castw<<<8192, 256, 0, stream>>>(gate_W, gateWb, 1024, 1024ull*2048, 2048, 2048, 2048, 0);
  k_castw<<<4096, 256, 0, stream>>>(dtrans_W, dtransWb, 1024, 1024ull*1024, 1024, 1024, 1024, 0);
  k_castw<<<3840, 256, 0, stream>>>(dWi0, dWi0e, 3072, 3072ull*320, 300, 320, 1324, 0);
  k_castw<<<12288, 256, 0, stream>>>(dWi0, dWi0c, 3072, 3072ull*1024, 1024, 1024, 1324, 300);
  k_castw<<<12288, 256, 0, stream>>>(dWh0, dWh0b, 3072, 3072ull*1024, 1024, 1024, 1024, 0);
  k_castw<<<12288, 256, 0, stream>>>(dWi1, dWi1b, 3072, 3072ull*1024, 1024, 1024, 1024, 0);
  k_castw<<<12288, 256, 0, stream>>>(dWh1, dWh1b, 3072, 3072ull*1024, 1024, 1024, 1024, 0);
  k_castw<<<8192, 256, 0, stream>>>(pW1, pW1b, 1024, 1024ull*2048, 2048, 2048, 2048, 0);

  hipMemsetAsync(bar, 0, 512, stream);

  // ---------------- encoder layer 0 ----------------
  k_mfma_nt<<<dim3(100,24,2), 256, 0, stream>>>(X0c, eWi0c, ebi0, GX, nullptr,
      6400, G3E, 384, 384, 384, G3E, 0, (long)G3E*384, 6400ull*G3E, G3E, 0, 0);
  hipMemsetAsync(hpp, 0, 2ull*2*NB*HENC*2, stream);
  k_scan_mfma<<<16, 256, 0, stream>>>(GX, GX + 6400ull*G3E, Whb0, ebh0,
      Y0bf, 0, hfin0, hpp, bar);
  // ---------------- encoder layer 1 ----------------
  k_mfma_nt<<<dim3(100,24,2), 256, 0, stream>>>(Y0bf, eWi1c, ebi1, GX, nullptr,
      6400, G3E, 1024, 1024, 1024, G3E, 0, (long)G3E*1024, 6400ull*G3E, G3E, 0, 0);
  hipMemsetAsync(hpp, 0, 2ull*2*NB*HENC*2, stream);
  k_scan_mfma<<<16, 256, 0, stream>>>(GX, GX + 6400ull*G3E, Whb1, ebh1,
      outpbf, 1, hfin1, hpp, bar + 64);

  // ---------------- self/answer attention ----------------
  k_mfma_nt<<<dim3(100,16,1), 256, 0, stream>>>(outpbf, transWb, trans_b, scratchC, memsbf,
      6400, HD2, 1024, 1024, 1024, HD2, 0, 0, 0, 0, 0, 0);
  k_mfma_nt<<<dim3(7,7,16), 256, 0, stream>>>(outpbf, memsbf, nullptr, energ, nullptr,
      TSN, TSN, 1024, 1024, 1024, TSN, (long)TSN*1024, (long)TSN*1024, (long)TSN*TSN, 0, 0, 0);
  k_softmax_bf<<<NB*TSN, 256, 0, stream>>>(energ, scoresb);
  k_transpose_hh<<<dim3(14,32,16), 256, 0, stream>>>(outpbf, outpTb);
  k_mfma_nt<<<dim3(7,16,16), 256, 0, stream>>>(scoresb, outpTb, nullptr, scratchC, ctx_bf,
      TSN, HD2, 448, 448, 448, HD2, (long)TSN*448, (long)HD2*448, (long)TSN*HD2, 0, 0, 0);
  k_mfma_nt<<<dim3(100,16,1), 256, 0, stream>>>(outpbf, updWb,        nullptr, ft, nullptr,
      6400, HD2, 1024, 1024, 2048, HD2, 0, 0, 0, 0, 0, 0);
  k_mfma_nt<<<dim3(100,16,1), 256, 0, stream>>>(ctx_bf, updWb + 1024, nullptr, ft, nullptr,
      6400, HD2, 1024, 1024, 2048, HD2, 0, 0, 0, 0, 1, 1);
  k_mfma_nt<<<dim3(100,16,1), 256, 0, stream>>>(outpbf, gateWb,       nullptr, scratchC, nullptr,
      6400, HD2, 1024, 1024, 2048, HD2, 0, 0, 0, 0, 0, 0);
  k_mfma_nt<<<dim3(100,16,1), 256, 0, stream>>>(ctx_bf, gateWb + 1024, nullptr, scratchC, nullptr,
      6400, HD2, 1024, 1024, 2048, HD2, 0, 0, 0, 0, 1, 2);
  k_ansatt2<<<64, 256, 0, stream>>>(memsbf, ft, scratchC, outpbf, input_a, encbf);
  // region now dead: cast pW2
  k_castw<<<200704, 256, 0, stream>>>(pW2, pW2b, NV, (long)NVP*1024, 1024, 1024, 1024, 0);
  k_mfma_nt<<<dim3(100,16,1), 256, 0, stream>>>(encbf, dtransWb, dtrans_b, scratchC, memd_bf,
      6400, HD2, 1024, 1024, 1024, HD2, 0, 0, 0, 0, 0, 0);

  // ---------------- decoder precompute ----------------
  k_embq_bf<<<640, 256, 0, stream>>>(dec_emb, input_q, embqb);
  k_mfma_nt<<<dim3(8,48,1), 256, 0, stream>>>(embqb, dWi0e, dbi0, embGX, nullptr,
      NTT*NB, G3D, 320, 320, 320, G3D, 0, 0, 0, 0, 0, 0);

  hipMemsetAsync(cov, 0, (size_t)NB*TSN*4, stream);
  hipMemsetAsync(covacc, 0, 4, stream);
  hipMemsetAsync(ubuf, 0, (size_t)NB*NEXT*4, stream);
  hipMemsetAsync(ctxbf, 0, (size_t)NB*HD2*2, stream);
  hipMemcpyAsync(dh0, hfin0, (size_t)NB*HD2*4, hipMemcpyDeviceToDevice, stream);
  hipMemcpyAsync(dh1, hfin1, (size_t)NB*HD2*4, hipMemcpyDeviceToDevice, stream);
  k_cast<<<64, 256, 0, stream>>>(hfin0, h0b, 16384);
  k_cast<<<64, 256, 0, stream>>>(hfin1, h1b, 16384);

  // ---------------- decoder steps (no logits in loop) ----------------
  for (int s = 0; s < NTT; ++s) {
    int cur = s & 1, nxt = cur ^ 1;
    float* h0c = dh0 + (size_t)cur*NB*HD2;  float* h0n = dh0 + (size_t)nxt*NB*HD2;
    float* h1c = dh1 + (size_t)cur*NB*HD2;  float* h1n = dh1 + (size_t)nxt*NB*HD2;
    ushort* h0bc = h0b + (size_t)cur*NB*HD2; ushort* h0bn = h0b + (size_t)nxt*NB*HD2;
    ushort* h1bc = h1b + (size_t)cur*NB*HD2; ushort* h1bn = h1b + (size_t)nxt*NB*HD2;
    ushort* ctxc = ctxbf + (size_t)cur*NB*HD2; ushort* ctxn = ctxbf + (size_t)nxt*NB*HD2;

    k_gru_dec<<<16, 256, 0, stream>>>(ctxc, dWi0c, h0bc, dWh0b,
        embGX + (size_t)s*NB*G3D, nullptr, dbh0, h0c, h0n, h0bn, nullptr);
    k_gru_dec<<<16, 256, 0, stream>>>(h0bn, dWi1b, h1bc, dWh1b,
        nullptr, dbi1, dbh1, h1c, h1n, h1bn, catbf);
    k_dec_attn2<<<NB, 1024, 0, stream>>>(h1bn, memd_bf,
        cov, coveAll + (size_t)s*NB*TSN, covacc, ctxn, catbf);
    k_hid<<<16, 256, 0, stream>>>(catbf, pW1b, pb1, hidAll + (size_t)s*NB*HD2);
  }
  // ---------------- batched logits + per-step compose ----------------
  k_logits_all<<<dim3(196, 4), 256, 0, stream>>>(hidAll, pW2b, pb2, out);
  for (int s = 0; s < NTT; ++s)
    k_compose<<<NB, 512, 0, stream>>>(ext_ids, coveAll, ubuf, out, s);
  k_covout<<<1, 1, 0, stream>>>(covacc, out);
}